// Round 12
// baseline (93.096 us; speedup 1.0000x reference)
//
#include <hip/hip_runtime.h>
#include <hip/hip_bf16.h>

// StridedAttention: y = (softmax(mask(QK^T/8)) V) Wo^T + bo, Q/K/V = x W{q,k,v}^T
// B=2 S=2048 D=1024 H=16 Dh=64 stride=64. Harness dtypes: f32 in/out.
// Both GEMMs: 128x128/BK=64, 8 waves, triple-buffer, counted vmcnt(4), 2 pinned
// phases/tile, row-XOR LDS swizzle. QKV grid = 768 blocks (3 full chip rounds,
// fixes the 192-block/0.75-chip underutilization of the 256x256 tile).
// Attention: dense 32x32 residue block per (b,h,r) via MFMA + 2 neighbor keys.

typedef __bf16 bf16;
typedef __attribute__((ext_vector_type(4))) __bf16 bf16x4;
typedef __attribute__((ext_vector_type(8))) __bf16 bf16x8;
typedef __attribute__((ext_vector_type(4))) float f32x4;
typedef __attribute__((ext_vector_type(4))) unsigned int u32x4;

constexpr int S_ = 2048;
constexpr int D_ = 1024;
constexpr int H_ = 16;
constexpr int DH = 64;
constexpr int M_ = 2 * S_;   // B*S = 4096 rows

__device__ __forceinline__ void gload_lds16(const bf16* g, bf16* l) {
    __builtin_amdgcn_global_load_lds(
        (const __attribute__((address_space(1))) void*)g,
        (__attribute__((address_space(3))) void*)l, 16, 0, 0);
}

#define BARRIER_FULL() do { asm volatile("" ::: "memory"); \
    __builtin_amdgcn_sched_barrier(0); \
    __builtin_amdgcn_s_barrier(); \
    __builtin_amdgcn_sched_barrier(0); \
    asm volatile("" ::: "memory"); } while (0)

#define WAIT_LGKM0() do { asm volatile("s_waitcnt lgkmcnt(0)" ::: "memory"); \
    __builtin_amdgcn_sched_barrier(0); } while (0)

#define WAIT_VM0() do { asm volatile("s_waitcnt vmcnt(0)" ::: "memory"); \
    __builtin_amdgcn_sched_barrier(0); } while (0)

#define WAIT_VM4() do { asm volatile("s_waitcnt vmcnt(4)" ::: "memory"); \
    __builtin_amdgcn_sched_barrier(0); } while (0)

// ---- BK=64 stage: per wave 2 x gload_lds of 8 rows (128B/row).
// Pre-swizzled source slot g = (lane&7) ^ (lane>>3); LDS dest linear; reads apply
// slot' = sIdx ^ (row&7) -> 2-way bank aliasing (free) instead of 16-way.
__device__ __forceinline__ void stage64(const bf16* __restrict__ G, int base_row,
                                        int kcol, bf16* lds, int wave, int lane)
{
    const int rIn = lane >> 3;                   // 0..7
    const int g   = (lane & 7) ^ rIn;            // src 16B slot
    #pragma unroll
    for (int l = 0; l < 2; ++l) {
        const int c = wave * 2 + l;              // 8-row chunk 0..15
        gload_lds16(G + (size_t)(base_row + c * 8 + rIn) * D_ + kcol + g * 8,
                    lds + c * 512);
    }
}

// ---------------- shared 128x128/BK=64 pipelined tile body ----------------
// OUT_BF16: write bf16 into C + z*M*D (z = n>>10, QKV); else f32 + bias (O-proj).
template<bool OUT_BF16>
__device__ __forceinline__ void gemm128_body(
    const bf16* __restrict__ A, const bf16* __restrict__ W,
    void* __restrict__ Cv, const float* __restrict__ bias,
    int bm, int bn, int wave, int lane)
{
    constexpr int BK = 64;
    constexpr int NT = D_ / BK;                  // 16 K-tiles
    constexpr int TSLOT = 128 * BK;              // 16 KB
    __shared__ __align__(16) bf16 As[3 * TSLOT]; // 48 KB
    __shared__ __align__(16) bf16 Bs[3 * TSLOT]; // 48 KB

    const int wm = wave >> 2;                    // 0..1 -> 64-row half
    const int wn = wave & 3;                     // 0..3 -> 32-col quarter
    const int l15 = lane & 15;
    const int hi  = lane >> 4;                   // 0..3
    const int r7  = l15 & 7;

    int aOff[2][4], bOff[2][2];
    #pragma unroll
    for (int ks = 0; ks < 2; ++ks) {
        #pragma unroll
        for (int fm = 0; fm < 4; ++fm)
            aOff[ks][fm] = (wm * 64 + fm * 16 + l15) * 64 + (((ks * 4 + hi) ^ r7) * 8);
        #pragma unroll
        for (int fn = 0; fn < 2; ++fn)
            bOff[ks][fn] = (wn * 32 + fn * 16 + l15) * 64 + (((ks * 4 + hi) ^ r7) * 8);
    }

    f32x4 acc[4][2];
    #pragma unroll
    for (int i = 0; i < 4; ++i)
        #pragma unroll
        for (int j = 0; j < 2; ++j) acc[i][j] = f32x4{0.f, 0.f, 0.f, 0.f};

    bf16x8 aF0[4], aF1[4], bF[2][2];

    // prologue: stage tiles 0 and 1; wait tile 0 only (tile 1 stays in flight)
    stage64(A, bm, 0,  As,         wave, lane);
    stage64(W, bn, 0,  Bs,         wave, lane);
    stage64(A, bm, BK, As + TSLOT, wave, lane);
    stage64(W, bn, BK, Bs + TSLOT, wave, lane);
    WAIT_VM4();
    BARRIER_FULL();

    int cur = 0;
    for (int t = 0; t < NT; ++t) {
        const int ss = (cur + 2 >= 3) ? (cur - 1) : (cur + 2);   // (cur+2)%3
        const bf16* aslot = As + cur * TSLOT;
        const bf16* bslot = Bs + cur * TSLOT;
        const bool pre = (t + 2) < NT;
        const int kn = (t + 2) * BK;

        // ---- phase 1: read B(both ksteps) + A(ks0); stage A(t+2); 8 MFMA ----
        #pragma unroll
        for (int ks = 0; ks < 2; ++ks)
            #pragma unroll
            for (int fn = 0; fn < 2; ++fn)
                bF[ks][fn] = *(const bf16x8*)(bslot + bOff[ks][fn]);
        #pragma unroll
        for (int fm = 0; fm < 4; ++fm)
            aF0[fm] = *(const bf16x8*)(aslot + aOff[0][fm]);
        if (pre) stage64(A, bm, kn, As + ss * TSLOT, wave, lane);
        BARRIER_FULL(); WAIT_LGKM0();
        __builtin_amdgcn_s_setprio(1);
        #pragma unroll
        for (int fm = 0; fm < 4; ++fm)
            #pragma unroll
            for (int fn = 0; fn < 2; ++fn)
                acc[fm][fn] = __builtin_amdgcn_mfma_f32_16x16x32_bf16(
                    aF0[fm], bF[0][fn], acc[fm][fn], 0, 0, 0);
        __builtin_amdgcn_s_setprio(0);
        BARRIER_FULL();

        // ---- phase 2: read A(ks1); stage W(t+2); 8 MFMA ----
        #pragma unroll
        for (int fm = 0; fm < 4; ++fm)
            aF1[fm] = *(const bf16x8*)(aslot + aOff[1][fm]);
        if (pre) stage64(W, bn, kn, Bs + ss * TSLOT, wave, lane);
        BARRIER_FULL(); WAIT_LGKM0();
        __builtin_amdgcn_s_setprio(1);
        #pragma unroll
        for (int fm = 0; fm < 4; ++fm)
            #pragma unroll
            for (int fn = 0; fn < 2; ++fn)
                acc[fm][fn] = __builtin_amdgcn_mfma_f32_16x16x32_bf16(
                    aF1[fm], bF[1][fn], acc[fm][fn], 0, 0, 0);
        __builtin_amdgcn_s_setprio(0);
        if (pre) { WAIT_VM4(); } else { WAIT_VM0(); }
        BARRIER_FULL();
        cur = (cur + 1 >= 3) ? 0 : (cur + 1);
    }

    // epilogue: m = bm + wm*64 + fm*16 + hi*4 + r2 ; n = bn + wn*32 + fn*16 + l15
    #pragma unroll
    for (int fm = 0; fm < 4; ++fm) {
        #pragma unroll
        for (int fn = 0; fn < 2; ++fn) {
            const int n = bn + wn * 32 + fn * 16 + l15;
            const int mb = bm + wm * 64 + fm * 16 + hi * 4;
            if (OUT_BF16) {
                bf16* Cz = (bf16*)Cv + (size_t)(n >> 10) * M_ * D_;
                const int col = n & 1023;
                #pragma unroll
                for (int r2 = 0; r2 < 4; ++r2)
                    Cz[(size_t)(mb + r2) * D_ + col] = (bf16)acc[fm][fn][r2];
            } else {
                const float bv = bias[n];
                #pragma unroll
                for (int r2 = 0; r2 < 4; ++r2)
                    ((float*)Cv)[(size_t)(mb + r2) * D_ + n] = acc[fm][fn][r2] + bv;
            }
        }
    }
}

// ---------------- QKV: C = x @ [Wq|Wk|Wv]^T, grid 24x32 = 768 blocks ----------------
__global__ __launch_bounds__(512, 1)
void gemm_qkv_128(const bf16* __restrict__ A,   // x   [4096,1024]
                  const bf16* __restrict__ W,   // Wq|Wk|Wv [3072,1024]
                  bf16* __restrict__ C)         // 3 x [4096,1024] contiguous
{
    const int wave = threadIdx.x >> 6;
    const int lane = threadIdx.x & 63;
    // XCD swizzle: 768 blocks, 96/XCD as 12x by 8y rect (W 3MB + A 2MB per XCD).
    const int lid = blockIdx.y * 24 + blockIdx.x;
    const int xcd = lid & 7, pos = lid >> 3;     // pos 0..95
    const int bxs = (xcd & 1) * 12 + pos % 12;
    const int bys = (xcd >> 1) * 8 + pos / 12;
    gemm128_body<true>(A, W, C, nullptr, bys * 128, bxs * 128, wave, lane);
}

// ---------------- O-proj: Cf = AO @ Wo^T + bo, grid 8x32 = 256 blocks ----------------
__global__ __launch_bounds__(512, 1)
void gemm_o_2ph(const bf16* __restrict__ A,     // AO [4096,1024] bf16
                const bf16* __restrict__ W,     // Wo [1024,1024] bf16
                float* __restrict__ Cf,         // [4096,1024] f32
                const float* __restrict__ bias)
{
    const int wave = threadIdx.x >> 6;
    const int lane = threadIdx.x & 63;
    // XCD swizzle: 256 blocks, 32/XCD as 2x by 16y rect.
    const int lid = blockIdx.y * 8 + blockIdx.x;
    const int xcd = lid & 7, pos = lid >> 3;     // pos 0..31
    const int bxs = (xcd & 3) * 2 + (pos & 1);
    const int bys = (xcd >> 2) * 16 + (pos >> 1);
    gemm128_body<false>(A, W, Cf, bias, bys * 128, bxs * 128, wave, lane);
}

// ---------------- 128x128 2-phase GEMM (fallback path only) ----------------
template<bool AF32, bool BF32, bool CF32, bool BIAS>
__global__ __launch_bounds__(256)
void gemm_bt(const void* __restrict__ Av,
             const void* __restrict__ W0v, const void* __restrict__ W1v,
             const void* __restrict__ W2v,
             void* __restrict__ Cv, const float* __restrict__ bias)
{
    constexpr int BM = 128, BK = 64;
    constexpr int N = D_, K = D_;
    __shared__ __align__(16) bf16 As[BM * BK];
    __shared__ __align__(16) bf16 Bs[BM * BK];

    const int z = blockIdx.z;
    const void* Wv_ = (z == 0) ? W0v : (z == 1) ? W1v : W2v;

    const int tid  = threadIdx.x;
    const int wave = tid >> 6;
    const int lane = tid & 63;

    const int bm = blockIdx.y * BM;
    const int bn = blockIdx.x * BM;
    const int wr = wave >> 1;
    const int wc = wave & 1;

    f32x4 acc[4][4];
    #pragma unroll
    for (int i = 0; i < 4; ++i)
        #pragma unroll
        for (int j = 0; j < 4; ++j)
            acc[i][j] = f32x4{0.f, 0.f, 0.f, 0.f};

    const int ldRow = lane >> 3;
    const int ldCol = (lane & 7) * 8;

    for (int kt = 0; kt < K; kt += BK) {
        if (AF32) {
            const float* A = (const float*)Av;
            #pragma unroll
            for (int it = 0; it < 8; ++it) {
                const int flat = (it * 256 + tid) * 4;
                const int row = flat >> 6, col = flat & 63;
                const float4 v = *(const float4*)(A + (size_t)(bm + row) * K + kt + col);
                bf16x4 p = { (bf16)v.x, (bf16)v.y, (bf16)v.z, (bf16)v.w };
                *(bf16x4*)&As[row * BK + col] = p;
            }
        } else {
            const bf16* A = (const bf16*)Av;
            #pragma unroll
            for (int q = 0; q < 4; ++q) {
                const int c = wave * 4 + q;
                const int row = c * 8 + ldRow;
                gload_lds16(A + (size_t)(bm + row) * K + kt + ldCol, &As[c * 8 * BK]);
            }
        }
        if (BF32) {
            const float* W = (const float*)Wv_;
            #pragma unroll
            for (int it = 0; it < 8; ++it) {
                const int flat = (it * 256 + tid) * 4;
                const int row = flat >> 6, col = flat & 63;
                const float4 v = *(const float4*)(W + (size_t)(bn + row) * K + kt + col);
                bf16x4 p = { (bf16)v.x, (bf16)v.y, (bf16)v.z, (bf16)v.w };
                *(bf16x4*)&Bs[row * BK + col] = p;
            }
        } else {
            const bf16* W = (const bf16*)Wv_;
            #pragma unroll
            for (int q = 0; q < 4; ++q) {
                const int c = wave * 4 + q;
                const int row = c * 8 + ldRow;
                gload_lds16(W + (size_t)(bn + row) * K + kt + ldCol, &Bs[c * 8 * BK]);
            }
        }
        __syncthreads();
        #pragma unroll
        for (int kk = 0; kk < 2; ++kk) {
            const int k0 = kk * 32 + (lane >> 4) * 8;
            bf16x8 af[4], bfv[4];
            #pragma unroll
            for (int mi = 0; mi < 4; ++mi)
                af[mi] = *(const bf16x8*)&As[(wr * 64 + mi * 16 + (lane & 15)) * BK + k0];
            #pragma unroll
            for (int ni = 0; ni < 4; ++ni)
                bfv[ni] = *(const bf16x8*)&Bs[(wc * 64 + ni * 16 + (lane & 15)) * BK + k0];
            #pragma unroll
            for (int mi = 0; mi < 4; ++mi)
                #pragma unroll
                for (int ni = 0; ni < 4; ++ni)
                    acc[mi][ni] = __builtin_amdgcn_mfma_f32_16x16x32_bf16(
                        af[mi], bfv[ni], acc[mi][ni], 0, 0, 0);
        }
        __syncthreads();
    }

    #pragma unroll
    for (int mi = 0; mi < 4; ++mi) {
        #pragma unroll
        for (int ni = 0; ni < 4; ++ni) {
            const int n  = bn + wc * 64 + ni * 16 + (lane & 15);
            const int mb = bm + wr * 64 + mi * 16 + (lane >> 4) * 4;
            float bv = 0.f;
            if (BIAS) bv = bias[n];
            #pragma unroll
            for (int r2 = 0; r2 < 4; ++r2) {
                const int m = mb + r2;
                if (CF32) {
                    ((float*)Cv)[(size_t)m * N + n] = acc[mi][ni][r2] + bv;
                } else {
                    bf16* Cc = (bf16*)Cv + (size_t)z * M_ * D_;
                    Cc[(size_t)m * N + n] = (bf16)(acc[mi][ni][r2] + bv);
                }
            }
        }
    }
}

// ---------------- f32 -> bf16 conversion: x | Wq | Wk | Wv | Wo ----------------
__global__ __launch_bounds__(256)
void convert_to_bf16(const float* __restrict__ x,
                     const float* __restrict__ w0, const float* __restrict__ w1,
                     const float* __restrict__ w2, const float* __restrict__ w3,
                     bf16* __restrict__ out)
{
    const size_t eid = ((size_t)blockIdx.x * 256 + threadIdx.x) * 8;
    const float* src; size_t off;
    if (eid < (size_t)(1u << 22)) { src = x; off = eid; }              // x: 2^22 elems
    else {
        const size_t t = eid - (1u << 22);
        const int k = (int)(t >> 20);                                   // W: 2^20 each
        off = t & ((1u << 20) - 1);
        src = (k == 0) ? w0 : (k == 1) ? w1 : (k == 2) ? w2 : w3;
    }
    const float4 a = *(const float4*)(src + off);
    const float4 c = *(const float4*)(src + off + 4);
    bf16x8 v = { (bf16)a.x, (bf16)a.y, (bf16)a.z, (bf16)a.w,
                 (bf16)c.x, (bf16)c.y, (bf16)c.z, (bf16)c.w };
    *(bf16x8*)(out + eid) = v;
}

// ---------------- MFMA sparse attention: one wave per (b,h,r) ----------------
__device__ __forceinline__ unsigned pk2bf(float lo, float hi) {
    const unsigned a = __builtin_bit_cast(unsigned short, (bf16)lo);
    const unsigned b = __builtin_bit_cast(unsigned short, (bf16)hi);
    return a | (b << 16);
}

__global__ __launch_bounds__(256)
void attn_mfma(bf16* __restrict__ QA, const bf16* __restrict__ Kw,
               const bf16* __restrict__ Vw)
{
    const int lane = threadIdx.x & 63;
    const int wid  = blockIdx.x * 4 + (threadIdx.x >> 6);
    const int r = wid & 63;                       // residue class
    const int h = (wid >> 6) & (H_ - 1);
    const int b = wid >> 10;

    const int qlo = lane & 15;
    const int g   = lane >> 4;                    // quarter-wave 0..3
    const size_t rb = (size_t)b * S_;
    const int col0 = h * DH;
    const float scale = 0.125f;                   // 1/sqrt(64)

    f32x4 accS[2][2];
    #pragma unroll
    for (int a = 0; a < 2; ++a)
        #pragma unroll
        for (int c = 0; c < 2; ++c) accS[a][c] = f32x4{0.f,0.f,0.f,0.f};

    #pragma unroll
    for (int c = 0; c < 2; ++c) {                 // d-chunks of 32
        bf16x8 kf[2], qf[2];
        #pragma unroll
        for (int t = 0; t < 2; ++t) {
            const size_t row = rb + (size_t)(r + 64 * (t * 16 + qlo));
            kf[t] = *(const bf16x8*)&Kw[row * D_ + col0 + c * 32 + g * 8];
            qf[t] = *(const bf16x8*)&QA[row * D_ + col0 + c * 32 + g * 8];
        }
        #pragma unroll
        for (int kt = 0; kt < 2; ++kt)
            #pragma unroll
            for (int qt = 0; qt < 2; ++qt)
                accS[kt][qt] = __builtin_amdgcn_mfma_f32_16x16x32_bf16(
                    kf[kt], qf[qt], accS[kt][qt], 0, 0, 0);
    }

    const int s_nb = lane & 31;
    const int side = lane >> 5;
    const int i_nb = r + 64 * s_nb;
    const int j_nb = side ? (i_nb + 1) : (i_nb - 1);
    const bool nbv = (unsigned)j_nb < (unsigned)S_;
    const int j_sf = nbv ? j_nb : i_nb;
    float nbd = 0.f;
    #pragma unroll
    for (int t = 0; t < 8; ++t) {
        const bf16x8 qv = *(const bf16x8*)&QA[(rb + i_nb) * D_ + col0 + t * 8];
        const bf16x8 kv = *(const bf16x8*)&Kw[(rb + j_sf) * D_ + col0 + t * 8];
        #pragma unroll
        for (int e = 0; e < 8; ++e) nbd += (float)qv[e] * (float)kv[e];
    }
    const float NEGINF = -__builtin_inff();
    float nb = nbv ? nbd * scale : NEGINF;

    float mx[2] = { NEGINF, NEGINF };
    #pragma unroll
    for (int kt = 0; kt < 2; ++kt)
        #pragma unroll
        for (int qt = 0; qt < 2; ++qt)
            #pragma unroll
            for (int rr = 0; rr < 4; ++rr)
                mx[qt] = fmaxf(mx[qt], accS[kt][qt][rr]);
    mx[0] *= scale; mx[1] *= scale;
    mx[g & 1] = fmaxf(mx[g & 1], nb);
    #pragma unroll
    for (int x = 16; x <= 32; x <<= 1) {
        mx[0] = fmaxf(mx[0], __shfl_xor(mx[0], x));
        mx[1] = fmaxf(mx[1], __shfl_xor(mx[1], x));
    }
    float p[2][2][4];
    float sm[2] = { 0.f, 0.f };
    #pragma unroll
    for (int kt = 0; kt < 2; ++kt)
        #pragma unroll
        for (int qt = 0; qt < 2; ++qt)
            #pragma unroll
            for (int rr = 0; rr < 4; ++rr) {
                const float e = __expf(accS[kt][qt][rr] * scale - mx[qt]);
                p[kt][qt][rr] = e;
                sm[qt] += e;
            }
    float nbp = __expf(nb - mx[g & 1]);
    sm[g & 1] += nbp;
    #pragma unroll
    for (int x = 16; x <= 32; x <<= 1) {
        sm[0] += __shfl_xor(sm[0], x);
        sm[1] += __shfl_xor(sm[1], x);
    }
    const float inv[2] = { 1.f / sm[0], 1.f / sm[1] };
    #pragma unroll
    for (int kt = 0; kt < 2; ++kt)
        #pragma unroll
        for (int qt = 0; qt < 2; ++qt)
            #pragma unroll
            for (int rr = 0; rr < 4; ++rr) p[kt][qt][rr] *= inv[qt];
    nbp *= inv[g & 1];

    unsigned pk_[2][2][2];                        // [qt][kt][w]
    #pragma unroll
    for (int qt = 0; qt < 2; ++qt)
        #pragma unroll
        for (int kt = 0; kt < 2; ++kt)
            #pragma unroll
            for (int w = 0; w < 2; ++w)
                pk_[qt][kt][w] = pk2bf(p[kt][qt][2 * w], p[kt][qt][2 * w + 1]);

    const int srcA = qlo + 32 * (g & 1);
    const int srcB = srcA + 16;
    const int kts  = g >> 1;
    bf16x8 pa[2];
    #pragma unroll
    for (int qt = 0; qt < 2; ++qt) {
        u32x4 fr;
        #pragma unroll
        for (int w = 0; w < 2; ++w) {
            const unsigned a0 = (unsigned)__shfl((int)pk_[qt][0][w], srcA);
            const unsigned a1 = (unsigned)__shfl((int)pk_[qt][1][w], srcA);
            fr[w] = kts ? a1 : a0;
            const unsigned b0 = (unsigned)__shfl((int)pk_[qt][0][w], srcB);
            const unsigned b1 = (unsigned)__shfl((int)pk_[qt][1][w], srcB);
            fr[2 + w] = kts ? b1 : b0;
        }
        pa[qt] = __builtin_bit_cast(bf16x8, fr);
    }

    f32x4 accO[2][4];
    #pragma unroll
    for (int qt = 0; qt < 2; ++qt)
        #pragma unroll
        for (int dt = 0; dt < 4; ++dt) accO[qt][dt] = f32x4{0.f,0.f,0.f,0.f};
    #pragma unroll
    for (int dt = 0; dt < 4; ++dt) {
        bf16x8 vf;
        #pragma unroll
        for (int e = 0; e < 8; ++e)
            vf[e] = Vw[(rb + (size_t)(r + 64 * (g * 8 + e))) * D_ + col0 + dt * 16 + qlo];
        accO[0][dt] = __builtin_amdgcn_mfma_f32_16x16x32_bf16(pa[0], vf, accO[0][dt], 0, 0, 0);
        accO[1][dt] = __builtin_amdgcn_mfma_f32_16x16x32_bf16(pa[1], vf, accO[1][dt], 0, 0, 0);
    }

    #pragma unroll
    for (int qt = 0; qt < 2; ++qt)
        #pragma unroll
        for (int rr = 0; rr < 4; ++rr) {
            const int q  = qt * 16 + g * 4 + rr;
            const int iq = r + 64 * q;
            const float pm = __shfl(nbp, q);
            const float pp = __shfl(nbp, q + 32);
            const int jm = iq > 0 ? iq - 1 : 0;
            const int jp = iq < S_ - 1 ? iq + 1 : S_ - 1;
            #pragma unroll
            for (int dt = 0; dt < 4; ++dt) {
                const int d = col0 + dt * 16 + qlo;
                const float vm = (float)Vw[(rb + jm) * D_ + d];
                const float vp = (float)Vw[(rb + jp) * D_ + d];
                const float o = accO[qt][dt][rr] + pm * vm + pp * vp;
                QA[(rb + iq) * D_ + d] = (bf16)o;
            }
        }
}

extern "C" void kernel_launch(void* const* d_in, const int* in_sizes, int n_in,
                              void* d_out, int out_size, void* d_ws, size_t ws_size,
                              hipStream_t stream)
{
    const float* x  = (const float*)d_in[0];
    const float* Wq = (const float*)d_in[1];
    const float* Wk = (const float*)d_in[2];
    const float* Wv = (const float*)d_in[3];
    const float* Wo = (const float*)d_in[4];
    const float* bo = (const float*)d_in[5];

    bf16* qws = (bf16*)d_ws;                        // 8 MB, becomes AO in place
    bf16* kws = qws + (size_t)M_ * D_;              // 8 MB
    bf16* vws = kws + (size_t)M_ * D_;              // 8 MB

    const bool fast = ws_size >= (size_t)40 * 1024 * 1024;

    if (fast) {
        bf16* xb  = vws + (size_t)M_ * D_;          // 8 MB
        bf16* wqb = xb + (1u << 22);                // Wq|Wk|Wv|Wo contiguous
        bf16* wob = wqb + 3 * (1u << 20);

        convert_to_bf16<<<4096, 256, 0, stream>>>(x, Wq, Wk, Wv, Wo, xb);

        // QKV: 768 blocks = 3 full chip rounds at 128x128
        gemm_qkv_128<<<dim3(3 * D_ / 128, M_ / 128), 512, 0, stream>>>(xb, wqb, qws);

        attn_mfma<<<dim3(2 * H_ * 64 / 4), 256, 0, stream>>>(qws, kws, vws);

        gemm_o_2ph<<<dim3(D_ / 128, M_ / 128), 512, 0, stream>>>(
            qws, wob, (float*)d_out, bo);
    } else {
        gemm_bt<true, true, false, false><<<dim3(D_/128, M_/128, 3), 256, 0, stream>>>(
            x, Wq, Wk, Wv, qws, nullptr);

        attn_mfma<<<dim3(2 * H_ * 64 / 4), 256, 0, stream>>>(qws, kws, vws);

        gemm_bt<false, true, true, true><<<dim3(D_/128, M_/128, 1), 256, 0, stream>>>(
            qws, Wo, nullptr, nullptr, (float*)d_out, bo);
    }
}

// Round 13
// 85.834 us; speedup vs baseline: 1.0846x; 1.0846x over previous
//
#include <hip/hip_runtime.h>
#include <hip/hip_bf16.h>

// StridedAttention: y = (softmax(mask(QK^T/8)) V) Wo^T + bo, Q/K/V = x W{q,k,v}^T
// B=2 S=2048 D=1024 H=16 Dh=64 stride=64. Harness dtypes: f32 in/out.
// QKV: m201-style 256x256/BK=64 8-wave schedule — 4 phases/K-tile, half-tile
// (128x64) staging one per phase, counted vmcnt(4) once per tile (never 0
// mid-loop), 2 barriers/phase, B-frags register-held across 3 phases.
// O-proj: 128x128/BK=64 2-phase (round-9 proven). Attention: dense 32x32
// residue block per (b,h,r) via MFMA + 2 neighbor keys.

typedef __bf16 bf16;
typedef __attribute__((ext_vector_type(4))) __bf16 bf16x4;
typedef __attribute__((ext_vector_type(8))) __bf16 bf16x8;
typedef __attribute__((ext_vector_type(4))) float f32x4;
typedef __attribute__((ext_vector_type(4))) unsigned int u32x4;

constexpr int S_ = 2048;
constexpr int D_ = 1024;
constexpr int H_ = 16;
constexpr int DH = 64;
constexpr int M_ = 2 * S_;   // B*S = 4096 rows

__device__ __forceinline__ void gload_lds16(const bf16* g, bf16* l) {
    __builtin_amdgcn_global_load_lds(
        (const __attribute__((address_space(1))) void*)g,
        (__attribute__((address_space(3))) void*)l, 16, 0, 0);
}

#define BARRIER_FULL() do { asm volatile("" ::: "memory"); \
    __builtin_amdgcn_sched_barrier(0); \
    __builtin_amdgcn_s_barrier(); \
    __builtin_amdgcn_sched_barrier(0); \
    asm volatile("" ::: "memory"); } while (0)

#define WAIT_LGKM0() do { asm volatile("s_waitcnt lgkmcnt(0)" ::: "memory"); \
    __builtin_amdgcn_sched_barrier(0); } while (0)

#define WAIT_VM0() do { asm volatile("s_waitcnt vmcnt(0)" ::: "memory"); \
    __builtin_amdgcn_sched_barrier(0); } while (0)

#define WAIT_VM4() do { asm volatile("s_waitcnt vmcnt(4)" ::: "memory"); \
    __builtin_amdgcn_sched_barrier(0); } while (0)

// ---- half-tile stager: [128 rows][64 cols] from row base_row, col kcol.
// Per wave 2 x gload_lds of 8 rows (128B/row). Pre-swizzled src slot
// g = (lane&7) ^ (lane>>3); LDS dest linear; reads apply slot' = sIdx ^ (row&7).
__device__ __forceinline__ void stage64(const bf16* __restrict__ G, int base_row,
                                        int kcol, bf16* lds, int wave, int lane)
{
    const int rIn = lane >> 3;                   // 0..7
    const int g   = (lane & 7) ^ rIn;            // src 16B slot
    #pragma unroll
    for (int l = 0; l < 2; ++l) {
        const int c = wave * 2 + l;              // 8-row chunk 0..15
        gload_lds16(G + (size_t)(base_row + c * 8 + rIn) * D_ + kcol + g * 8,
                    lds + c * 512);
    }
}

// ---------------- QKV: C = x @ [Wq|Wk|Wv]^T, 256x256, m201-style ----------------
// Half-tile pipeline (race-checked): tile t (dbuf d=t&1) stages
//   P1 -> (t+1).A1 [d^1]   (A-half1 of d^1 last read at t-1's P3; t-1 done)
//   P2 -> (t+1).B1 [d^1]   (B-half1 of d^1 last read at t-1's P2)
//   P3 -> (t+2).B0 [d]     (B-half0 of d last read THIS tile at P2; P3 > P2)
//   P4 -> (t+2).A0 [d]     (A-half0 of d last read THIS tile at P3; P4 > P3)
// vmcnt(4) at end of P4 leaves only (t+2).B0/(t+2).A0 (4 loads) outstanding,
// so tile t+1's four halves are all confirmed-landed before its P1 reads.
__global__ __launch_bounds__(512, 1)
void gemm_qkv_8p(const bf16* __restrict__ A,    // x   [4096,1024]
                 const bf16* __restrict__ W,    // Wq|Wk|Wv [3072,1024]
                 bf16* __restrict__ C)          // 3 x [4096,1024] contiguous
{
    constexpr int BK = 64;
    constexpr int NT = D_ / BK;                    // 16 K-tiles
    constexpr int HS = 128 * BK;                   // half-tile: 8192 elems = 16 KB
    __shared__ __align__(16) bf16 As[2][2][HS];    // [dbuf][half] 64 KB
    __shared__ __align__(16) bf16 Bs[2][2][HS];    // 64 KB

    const int tid  = threadIdx.x;
    const int wave = tid >> 6;
    const int lane = tid & 63;
    const int wm = wave >> 2;                      // 0..1: 128-row half of C
    const int wn = wave & 3;                       // 0..3: 64-col quarter of C

    // XCD-chunked swizzle: grid 12x16 = 192 blocks, 24/XCD as a 6x by 4y rect.
    const int lid = blockIdx.y * 12 + blockIdx.x;
    const int xcd = lid & 7, pos = lid >> 3;
    const int bxs = (xcd & 1) * 6 + pos % 6;
    const int bys = (xcd >> 1) * 4 + pos / 6;
    const int bm = bys * 256;
    const int bn = bxs * 256;

    const int l15 = lane & 15;
    const int hi  = lane >> 4;
    const int r7  = l15 & 7;
    const int bh  = wn >> 1;                       // B half this wave reads

    // element offsets within a half [128][64] (row-XOR swizzled 16B slots)
    int aOff[2][4][2], bOff[2][2][2];              // [mh][fm][kk] / [nh][fn][kk]
    #pragma unroll
    for (int mh = 0; mh < 2; ++mh)
        #pragma unroll
        for (int fm = 0; fm < 4; ++fm)
            #pragma unroll
            for (int kk = 0; kk < 2; ++kk)
                aOff[mh][fm][kk] = (mh * 64 + fm * 16 + l15) * 64
                                 + (((kk * 4 + hi) ^ r7) * 8);
    #pragma unroll
    for (int nh = 0; nh < 2; ++nh)
        #pragma unroll
        for (int fn = 0; fn < 2; ++fn)
            #pragma unroll
            for (int kk = 0; kk < 2; ++kk)
                bOff[nh][fn][kk] = ((wn & 1) * 64 + nh * 32 + fn * 16 + l15) * 64
                                 + (((kk * 4 + hi) ^ r7) * 8);

    f32x4 acc[8][4];
    #pragma unroll
    for (int i = 0; i < 8; ++i)
        #pragma unroll
        for (int j = 0; j < 4; ++j) acc[i][j] = f32x4{0.f, 0.f, 0.f, 0.f};

    bf16x8 aF[4][2], bF0[2][2], bF1[2][2];

#define Q16(MH, NH, BF) do { _Pragma("unroll") \
    for (int fm = 0; fm < 4; ++fm) { _Pragma("unroll") \
        for (int fn = 0; fn < 2; ++fn) { _Pragma("unroll") \
            for (int kk = 0; kk < 2; ++kk) \
                acc[(MH)*4+fm][(NH)*2+fn] = __builtin_amdgcn_mfma_f32_16x16x32_bf16( \
                    aF[fm][kk], BF[fn][kk], acc[(MH)*4+fm][(NH)*2+fn], 0, 0, 0); \
    } } } while (0)

    // prologue: t0 all 4 halves + t1.B0 + t1.A0 ; vmcnt(4) -> t0 landed
    stage64(A, bm +   0, 0,  &As[0][0][0], wave, lane);
    stage64(A, bm + 128, 0,  &As[0][1][0], wave, lane);
    stage64(W, bn +   0, 0,  &Bs[0][0][0], wave, lane);
    stage64(W, bn + 128, 0,  &Bs[0][1][0], wave, lane);
    stage64(W, bn +   0, BK, &Bs[1][0][0], wave, lane);
    stage64(A, bm +   0, BK, &As[1][0][0], wave, lane);
    WAIT_VM4();
    BARRIER_FULL();

    for (int t = 0; t < NT; ++t) {
        const int d = t & 1;
        const bf16* aH = &As[d][wm][0];            // this wave's A half
        const bf16* bH = &Bs[d][bh][0];            // this wave's B half
        const bool pre1 = (t + 1) < NT;
        const bool pre2 = (t + 2) < NT;
        const int k1 = (t + 1) * BK, k2 = (t + 2) * BK;

        // ---- P1: read A(mh0) 8 + B(nh0) 4; stage (t+1).A1; MFMA Q(0,0) ----
        #pragma unroll
        for (int fn = 0; fn < 2; ++fn)
            #pragma unroll
            for (int kk = 0; kk < 2; ++kk)
                bF0[fn][kk] = *(const bf16x8*)(bH + bOff[0][fn][kk]);
        #pragma unroll
        for (int fm = 0; fm < 4; ++fm)
            #pragma unroll
            for (int kk = 0; kk < 2; ++kk)
                aF[fm][kk] = *(const bf16x8*)(aH + aOff[0][fm][kk]);
        if (pre1) stage64(A, bm + 128, k1, &As[d ^ 1][1][0], wave, lane);
        BARRIER_FULL(); WAIT_LGKM0();
        __builtin_amdgcn_s_setprio(1); Q16(0, 0, bF0); __builtin_amdgcn_s_setprio(0);
        BARRIER_FULL();

        // ---- P2: read B(nh1) 4; stage (t+1).B1; MFMA Q(0,1) ----
        #pragma unroll
        for (int fn = 0; fn < 2; ++fn)
            #pragma unroll
            for (int kk = 0; kk < 2; ++kk)
                bF1[fn][kk] = *(const bf16x8*)(bH + bOff[1][fn][kk]);
        if (pre1) stage64(W, bn + 128, k1, &Bs[d ^ 1][1][0], wave, lane);
        BARRIER_FULL(); WAIT_LGKM0();
        __builtin_amdgcn_s_setprio(1); Q16(0, 1, bF1); __builtin_amdgcn_s_setprio(0);
        BARRIER_FULL();

        // ---- P3: read A(mh1) 8 (overwrite aF); stage (t+2).B0; MFMA Q(1,1) ----
        #pragma unroll
        for (int fm = 0; fm < 4; ++fm)
            #pragma unroll
            for (int kk = 0; kk < 2; ++kk)
                aF[fm][kk] = *(const bf16x8*)(aH + aOff[1][fm][kk]);
        if (pre2) stage64(W, bn + 0, k2, &Bs[d][0][0], wave, lane);
        BARRIER_FULL(); WAIT_LGKM0();
        __builtin_amdgcn_s_setprio(1); Q16(1, 1, bF1); __builtin_amdgcn_s_setprio(0);
        BARRIER_FULL();

        // ---- P4: no reads; stage (t+2).A0; MFMA Q(1,0); counted vmcnt ----
        if (pre2) stage64(A, bm + 0, k2, &As[d][0][0], wave, lane);
        __builtin_amdgcn_s_setprio(1); Q16(1, 0, bF0); __builtin_amdgcn_s_setprio(0);
        if (pre2) { WAIT_VM4(); } else { WAIT_VM0(); }
        BARRIER_FULL();
    }
#undef Q16

    // epilogue: m = bm + wm*128 + i*16 + hi*4 + r2 ; n = bn + wn*64 + j*16 + l15
    #pragma unroll
    for (int i = 0; i < 8; ++i) {
        #pragma unroll
        for (int j = 0; j < 4; ++j) {
            const int n = bn + wn * 64 + j * 16 + l15;
            bf16* Cz = C + (size_t)(n >> 10) * M_ * D_;
            const int col = n & 1023;
            const int mb = bm + wm * 128 + i * 16 + hi * 4;
            #pragma unroll
            for (int r2 = 0; r2 < 4; ++r2)
                Cz[(size_t)(mb + r2) * D_ + col] = (bf16)acc[i][j][r2];
        }
    }
}

// ---------------- O-proj: Cf = AO @ Wo^T + bo, 128x128/BK=64, 8 waves (r9) ----
__global__ __launch_bounds__(512, 1)
void gemm_o_2ph(const bf16* __restrict__ A,     // AO [4096,1024] bf16
                const bf16* __restrict__ W,     // Wo [1024,1024] bf16
                float* __restrict__ Cf,         // [4096,1024] f32
                const float* __restrict__ bias)
{
    constexpr int BK = 64;
    constexpr int NT = D_ / BK;                  // 16 K-tiles
    constexpr int TSLOT = 128 * BK;              // 16 KB
    __shared__ __align__(16) bf16 As[3 * TSLOT]; // 48 KB
    __shared__ __align__(16) bf16 Bs[3 * TSLOT]; // 48 KB

    const int tid  = threadIdx.x;
    const int wave = tid >> 6;                   // 0..7
    const int lane = tid & 63;
    const int wm = wave >> 2;
    const int wn = wave & 3;

    // XCD swizzle: grid 8x32 = 256 blocks, 32/XCD as 2x by 16y rect.
    const int lid = blockIdx.y * 8 + blockIdx.x;
    const int xcd = lid & 7, pos = lid >> 3;
    const int bxs = (xcd & 3) * 2 + (pos & 1);
    const int bys = (xcd >> 2) * 16 + (pos >> 1);
    const int bm = bys * 128;
    const int bn = bxs * 128;

    const int l15 = lane & 15;
    const int hi  = lane >> 4;
    const int r7  = l15 & 7;

    int aOff[2][4], bOff[2][2];
    #pragma unroll
    for (int ks = 0; ks < 2; ++ks) {
        #pragma unroll
        for (int fm = 0; fm < 4; ++fm)
            aOff[ks][fm] = (wm * 64 + fm * 16 + l15) * 64 + (((ks * 4 + hi) ^ r7) * 8);
        #pragma unroll
        for (int fn = 0; fn < 2; ++fn)
            bOff[ks][fn] = (wn * 32 + fn * 16 + l15) * 64 + (((ks * 4 + hi) ^ r7) * 8);
    }

    f32x4 acc[4][2];
    #pragma unroll
    for (int i = 0; i < 4; ++i)
        #pragma unroll
        for (int j = 0; j < 2; ++j) acc[i][j] = f32x4{0.f, 0.f, 0.f, 0.f};

    bf16x8 aF0[4], aF1[4], bF[2][2];

    stage64(A, bm, 0,  As,         wave, lane);
    stage64(W, bn, 0,  Bs,         wave, lane);
    stage64(A, bm, BK, As + TSLOT, wave, lane);
    stage64(W, bn, BK, Bs + TSLOT, wave, lane);
    WAIT_VM4();
    BARRIER_FULL();

    int cur = 0;
    for (int t = 0; t < NT; ++t) {
        const int ss = (cur + 2 >= 3) ? (cur - 1) : (cur + 2);
        const bf16* aslot = As + cur * TSLOT;
        const bf16* bslot = Bs + cur * TSLOT;
        const bool pre = (t + 2) < NT;
        const int kn = (t + 2) * BK;

        #pragma unroll
        for (int ks = 0; ks < 2; ++ks)
            #pragma unroll
            for (int fn = 0; fn < 2; ++fn)
                bF[ks][fn] = *(const bf16x8*)(bslot + bOff[ks][fn]);
        #pragma unroll
        for (int fm = 0; fm < 4; ++fm)
            aF0[fm] = *(const bf16x8*)(aslot + aOff[0][fm]);
        if (pre) stage64(A, bm, kn, As + ss * TSLOT, wave, lane);
        BARRIER_FULL(); WAIT_LGKM0();
        __builtin_amdgcn_s_setprio(1);
        #pragma unroll
        for (int fm = 0; fm < 4; ++fm)
            #pragma unroll
            for (int fn = 0; fn < 2; ++fn)
                acc[fm][fn] = __builtin_amdgcn_mfma_f32_16x16x32_bf16(
                    aF0[fm], bF[0][fn], acc[fm][fn], 0, 0, 0);
        __builtin_amdgcn_s_setprio(0);
        BARRIER_FULL();

        #pragma unroll
        for (int fm = 0; fm < 4; ++fm)
            aF1[fm] = *(const bf16x8*)(aslot + aOff[1][fm]);
        if (pre) stage64(W, bn, kn, Bs + ss * TSLOT, wave, lane);
        BARRIER_FULL(); WAIT_LGKM0();
        __builtin_amdgcn_s_setprio(1);
        #pragma unroll
        for (int fm = 0; fm < 4; ++fm)
            #pragma unroll
            for (int fn = 0; fn < 2; ++fn)
                acc[fm][fn] = __builtin_amdgcn_mfma_f32_16x16x32_bf16(
                    aF1[fm], bF[1][fn], acc[fm][fn], 0, 0, 0);
        __builtin_amdgcn_s_setprio(0);
        if (pre) { WAIT_VM4(); } else { WAIT_VM0(); }
        BARRIER_FULL();
        cur = (cur + 1 >= 3) ? 0 : (cur + 1);
    }

    #pragma unroll
    for (int fm = 0; fm < 4; ++fm) {
        #pragma unroll
        for (int fn = 0; fn < 2; ++fn) {
            const int n = bn + wn * 32 + fn * 16 + l15;
            const float bv = bias[n];
            const int mb = bm + wm * 64 + fm * 16 + hi * 4;
            #pragma unroll
            for (int r2 = 0; r2 < 4; ++r2)
                Cf[(size_t)(mb + r2) * D_ + n] = acc[fm][fn][r2] + bv;
        }
    }
}

// ---------------- 128x128 2-phase GEMM (fallback path only) ----------------
template<bool AF32, bool BF32, bool CF32, bool BIAS>
__global__ __launch_bounds__(256)
void gemm_bt(const void* __restrict__ Av,
             const void* __restrict__ W0v, const void* __restrict__ W1v,
             const void* __restrict__ W2v,
             void* __restrict__ Cv, const float* __restrict__ bias)
{
    constexpr int BM = 128, BK = 64;
    constexpr int N = D_, K = D_;
    __shared__ __align__(16) bf16 As[BM * BK];
    __shared__ __align__(16) bf16 Bs[BM * BK];

    const int z = blockIdx.z;
    const void* Wv_ = (z == 0) ? W0v : (z == 1) ? W1v : W2v;

    const int tid  = threadIdx.x;
    const int wave = tid >> 6;
    const int lane = tid & 63;

    const int bm = blockIdx.y * BM;
    const int bn = blockIdx.x * BM;
    const int wr = wave >> 1;
    const int wc = wave & 1;

    f32x4 acc[4][4];
    #pragma unroll
    for (int i = 0; i < 4; ++i)
        #pragma unroll
        for (int j = 0; j < 4; ++j)
            acc[i][j] = f32x4{0.f, 0.f, 0.f, 0.f};

    const int ldRow = lane >> 3;
    const int ldCol = (lane & 7) * 8;

    for (int kt = 0; kt < K; kt += BK) {
        if (AF32) {
            const float* A = (const float*)Av;
            #pragma unroll
            for (int it = 0; it < 8; ++it) {
                const int flat = (it * 256 + tid) * 4;
                const int row = flat >> 6, col = flat & 63;
                const float4 v = *(const float4*)(A + (size_t)(bm + row) * K + kt + col);
                bf16x4 p = { (bf16)v.x, (bf16)v.y, (bf16)v.z, (bf16)v.w };
                *(bf16x4*)&As[row * BK + col] = p;
            }
        } else {
            const bf16* A = (const bf16*)Av;
            #pragma unroll
            for (int q = 0; q < 4; ++q) {
                const int c = wave * 4 + q;
                const int row = c * 8 + ldRow;
                gload_lds16(A + (size_t)(bm + row) * K + kt + ldCol, &As[c * 8 * BK]);
            }
        }
        if (BF32) {
            const float* W = (const float*)Wv_;
            #pragma unroll
            for (int it = 0; it < 8; ++it) {
                const int flat = (it * 256 + tid) * 4;
                const int row = flat >> 6, col = flat & 63;
                const float4 v = *(const float4*)(W + (size_t)(bn + row) * K + kt + col);
                bf16x4 p = { (bf16)v.x, (bf16)v.y, (bf16)v.z, (bf16)v.w };
                *(bf16x4*)&Bs[row * BK + col] = p;
            }
        } else {
            const bf16* W = (const bf16*)Wv_;
            #pragma unroll
            for (int q = 0; q < 4; ++q) {
                const int c = wave * 4 + q;
                const int row = c * 8 + ldRow;
                gload_lds16(W + (size_t)(bn + row) * K + kt + ldCol, &Bs[c * 8 * BK]);
            }
        }
        __syncthreads();
        #pragma unroll
        for (int kk = 0; kk < 2; ++kk) {
            const int k0 = kk * 32 + (lane >> 4) * 8;
            bf16x8 af[4], bfv[4];
            #pragma unroll
            for (int mi = 0; mi < 4; ++mi)
                af[mi] = *(const bf16x8*)&As[(wr * 64 + mi * 16 + (lane & 15)) * BK + k0];
            #pragma unroll
            for (int ni = 0; ni < 4; ++ni)
                bfv[ni] = *(const bf16x8*)&Bs[(wc * 64 + ni * 16 + (lane & 15)) * BK + k0];
            #pragma unroll
            for (int mi = 0; mi < 4; ++mi)
                #pragma unroll
                for (int ni = 0; ni < 4; ++ni)
                    acc[mi][ni] = __builtin_amdgcn_mfma_f32_16x16x32_bf16(
                        af[mi], bfv[ni], acc[mi][ni], 0, 0, 0);
        }
        __syncthreads();
    }

    #pragma unroll
    for (int mi = 0; mi < 4; ++mi) {
        #pragma unroll
        for (int ni = 0; ni < 4; ++ni) {
            const int n  = bn + wc * 64 + ni * 16 + (lane & 15);
            const int mb = bm + wr * 64 + mi * 16 + (lane >> 4) * 4;
            float bv = 0.f;
            if (BIAS) bv = bias[n];
            #pragma unroll
            for (int r2 = 0; r2 < 4; ++r2) {
                const int m = mb + r2;
                if (CF32) {
                    ((float*)Cv)[(size_t)m * N + n] = acc[mi][ni][r2] + bv;
                } else {
                    bf16* Cc = (bf16*)Cv + (size_t)z * M_ * D_;
                    Cc[(size_t)m * N + n] = (bf16)(acc[mi][ni][r2] + bv);
                }
            }
        }
    }
}

// ---------------- f32 -> bf16 conversion: x | Wq | Wk | Wv | Wo ----------------
__global__ __launch_bounds__(256)
void convert_to_bf16(const float* __restrict__ x,
                     const float* __restrict__ w0, const float* __restrict__ w1,
                     const float* __restrict__ w2, const float* __restrict__ w3,
                     bf16* __restrict__ out)
{
    const size_t eid = ((size_t)blockIdx.x * 256 + threadIdx.x) * 8;
    const float* src; size_t off;
    if (eid < (size_t)(1u << 22)) { src = x; off = eid; }              // x: 2^22 elems
    else {
        const size_t t = eid - (1u << 22);
        const int k = (int)(t >> 20);                                   // W: 2^20 each
        off = t & ((1u << 20) - 1);
        src = (k == 0) ? w0 : (k == 1) ? w1 : (k == 2) ? w2 : w3;
    }
    const float4 a = *(const float4*)(src + off);
    const float4 c = *(const float4*)(src + off + 4);
    bf16x8 v = { (bf16)a.x, (bf16)a.y, (bf16)a.z, (bf16)a.w,
                 (bf16)c.x, (bf16)c.y, (bf16)c.z, (bf16)c.w };
    *(bf16x8*)(out + eid) = v;
}

// ---------------- MFMA sparse attention: one wave per (b,h,r) ----------------
__device__ __forceinline__ unsigned pk2bf(float lo, float hi) {
    const unsigned a = __builtin_bit_cast(unsigned short, (bf16)lo);
    const unsigned b = __builtin_bit_cast(unsigned short, (bf16)hi);
    return a | (b << 16);
}

__global__ __launch_bounds__(256)
void attn_mfma(bf16* __restrict__ QA, const bf16* __restrict__ Kw,
               const bf16* __restrict__ Vw)
{
    const int lane = threadIdx.x & 63;
    const int wid  = blockIdx.x * 4 + (threadIdx.x >> 6);
    const int r = wid & 63;                       // residue class
    const int h = (wid >> 6) & (H_ - 1);
    const int b = wid >> 10;

    const int qlo = lane & 15;
    const int g   = lane >> 4;                    // quarter-wave 0..3
    const size_t rb = (size_t)b * S_;
    const int col0 = h * DH;
    const float scale = 0.125f;                   // 1/sqrt(64)

    f32x4 accS[2][2];
    #pragma unroll
    for (int a = 0; a < 2; ++a)
        #pragma unroll
        for (int c = 0; c < 2; ++c) accS[a][c] = f32x4{0.f,0.f,0.f,0.f};

    #pragma unroll
    for (int c = 0; c < 2; ++c) {                 // d-chunks of 32
        bf16x8 kf[2], qf[2];
        #pragma unroll
        for (int t = 0; t < 2; ++t) {
            const size_t row = rb + (size_t)(r + 64 * (t * 16 + qlo));
            kf[t] = *(const bf16x8*)&Kw[row * D_ + col0 + c * 32 + g * 8];
            qf[t] = *(const bf16x8*)&QA[row * D_ + col0 + c * 32 + g * 8];
        }
        #pragma unroll
        for (int kt = 0; kt < 2; ++kt)
            #pragma unroll
            for (int qt = 0; qt < 2; ++qt)
                accS[kt][qt] = __builtin_amdgcn_mfma_f32_16x16x32_bf16(
                    kf[kt], qf[qt], accS[kt][qt], 0, 0, 0);
    }

    const int s_nb = lane & 31;
    const int side = lane >> 5;
    const int i_nb = r + 64 * s_nb;
    const int j_nb = side ? (i_nb + 1) : (i_nb - 1);
    const bool nbv = (unsigned)j_nb < (unsigned)S_;
    const int j_sf = nbv ? j_nb : i_nb;
    float nbd = 0.f;
    #pragma unroll
    for (int t = 0; t < 8; ++t) {
        const bf16x8 qv = *(const bf16x8*)&QA[(rb + i_nb) * D_ + col0 + t * 8];
        const bf16x8 kv = *(const bf16x8*)&Kw[(rb + j_sf) * D_ + col0 + t * 8];
        #pragma unroll
        for (int e = 0; e < 8; ++e) nbd += (float)qv[e] * (float)kv[e];
    }
    const float NEGINF = -__builtin_inff();
    float nb = nbv ? nbd * scale : NEGINF;

    float mx[2] = { NEGINF, NEGINF };
    #pragma unroll
    for (int kt = 0; kt < 2; ++kt)
        #pragma unroll
        for (int qt = 0; qt < 2; ++qt)
            #pragma unroll
            for (int rr = 0; rr < 4; ++rr)
                mx[qt] = fmaxf(mx[qt], accS[kt][qt][rr]);
    mx[0] *= scale; mx[1] *= scale;
    mx[g & 1] = fmaxf(mx[g & 1], nb);
    #pragma unroll
    for (int x = 16; x <= 32; x <<= 1) {
        mx[0] = fmaxf(mx[0], __shfl_xor(mx[0], x));
        mx[1] = fmaxf(mx[1], __shfl_xor(mx[1], x));
    }
    float p[2][2][4];
    float sm[2] = { 0.f, 0.f };
    #pragma unroll
    for (int kt = 0; kt < 2; ++kt)
        #pragma unroll
        for (int qt = 0; qt < 2; ++qt)
            #pragma unroll
            for (int rr = 0; rr < 4; ++rr) {
                const float e = __expf(accS[kt][qt][rr] * scale - mx[qt]);
                p[kt][qt][rr] = e;
                sm[qt] += e;
            }
    float nbp = __expf(nb - mx[g & 1]);
    sm[g & 1] += nbp;
    #pragma unroll
    for (int x = 16; x <= 32; x <<= 1) {
        sm[0] += __shfl_xor(sm[0], x);
        sm[1] += __shfl_xor(sm[1], x);
    }
    const float inv[2] = { 1.f / sm[0], 1.f / sm[1] };
    #pragma unroll
    for (int kt = 0; kt < 2; ++kt)
        #pragma unroll
        for (int qt = 0; qt < 2; ++qt)
            #pragma unroll
            for (int rr = 0; rr < 4; ++rr) p[kt][qt][rr] *= inv[qt];
    nbp *= inv[g & 1];

    unsigned pk_[2][2][2];                        // [qt][kt][w]
    #pragma unroll
    for (int qt = 0; qt < 2; ++qt)
        #pragma unroll
        for (int kt = 0; kt < 2; ++kt)
            #pragma unroll
            for (int w = 0; w < 2; ++w)
                pk_[qt][kt][w] = pk2bf(p[kt][qt][2 * w], p[kt][qt][2 * w + 1]);

    const int srcA = qlo + 32 * (g & 1);
    const int srcB = srcA + 16;
    const int kts  = g >> 1;
    bf16x8 pa[2];
    #pragma unroll
    for (int qt = 0; qt < 2; ++qt) {
        u32x4 fr;
        #pragma unroll
        for (int w = 0; w < 2; ++w) {
            const unsigned a0 = (unsigned)__shfl((int)pk_[qt][0][w], srcA);
            const unsigned a1 = (unsigned)__shfl((int)pk_[qt][1][w], srcA);
            fr[w] = kts ? a1 : a0;
            const unsigned b0 = (unsigned)__shfl((int)pk_[qt][0][w], srcB);
            const unsigned b1 = (unsigned)__shfl((int)pk_[qt][1][w], srcB);
            fr[2 + w] = kts ? b1 : b0;
        }
        pa[qt] = __builtin_bit_cast(bf16x8, fr);
    }

    f32x4 accO[2][4];
    #pragma unroll
    for (int qt = 0; qt < 2; ++qt)
        #pragma unroll
        for (int dt = 0; dt < 4; ++dt) accO[qt][dt] = f32x4{0.f,0.f,0.f,0.f};
    #pragma unroll
    for (int dt = 0; dt < 4; ++dt) {
        bf16x8 vf;
        #pragma unroll
        for (int e = 0; e < 8; ++e)
            vf[e] = Vw[(rb + (size_t)(r + 64 * (g * 8 + e))) * D_ + col0 + dt * 16 + qlo];
        accO[0][dt] = __builtin_amdgcn_mfma_f32_16x16x32_bf16(pa[0], vf, accO[0][dt], 0, 0, 0);
        accO[1][dt] = __builtin_amdgcn_mfma_f32_16x16x32_bf16(pa[1], vf, accO[1][dt], 0, 0, 0);
    }

    #pragma unroll
    for (int qt = 0; qt < 2; ++qt)
        #pragma unroll
        for (int rr = 0; rr < 4; ++rr) {
            const int q  = qt * 16 + g * 4 + rr;
            const int iq = r + 64 * q;
            const float pm = __shfl(nbp, q);
            const float pp = __shfl(nbp, q + 32);
            const int jm = iq > 0 ? iq - 1 : 0;
            const int jp = iq < S_ - 1 ? iq + 1 : S_ - 1;
            #pragma unroll
            for (int dt = 0; dt < 4; ++dt) {
                const int d = col0 + dt * 16 + qlo;
                const float vm = (float)Vw[(rb + jm) * D_ + d];
                const float vp = (float)Vw[(rb + jp) * D_ + d];
                const float o = accO[qt][dt][rr] + pm * vm + pp * vp;
                QA[(rb + iq) * D_ + d] = (bf16)o;
            }
        }
}

extern "C" void kernel_launch(void* const* d_in, const int* in_sizes, int n_in,
                              void* d_out, int out_size, void* d_ws, size_t ws_size,
                              hipStream_t stream)
{
    const float* x  = (const float*)d_in[0];
    const float* Wq = (const float*)d_in[1];
    const float* Wk = (const float*)d_in[2];
    const float* Wv = (const float*)d_in[3];
    const float* Wo = (const float*)d_in[4];
    const float* bo = (const float*)d_in[5];

    bf16* qws = (bf16*)d_ws;                        // 8 MB, becomes AO in place
    bf16* kws = qws + (size_t)M_ * D_;              // 8 MB
    bf16* vws = kws + (size_t)M_ * D_;              // 8 MB

    const bool fast = ws_size >= (size_t)40 * 1024 * 1024;

    if (fast) {
        bf16* xb  = vws + (size_t)M_ * D_;          // 8 MB
        bf16* wqb = xb + (1u << 22);                // Wq|Wk|Wv|Wo contiguous
        bf16* wob = wqb + 3 * (1u << 20);

        convert_to_bf16<<<4096, 256, 0, stream>>>(x, Wq, Wk, Wv, Wo, xb);

        // QKV: 256x256 m201-style half-tile pipeline, grid 12x16
        gemm_qkv_8p<<<dim3(3 * D_ / 256, M_ / 256), 512, 0, stream>>>(xb, wqb, qws);

        attn_mfma<<<dim3(2 * H_ * 64 / 4), 256, 0, stream>>>(qws, kws, vws);

        gemm_o_2ph<<<dim3(D_ / 128, M_ / 128), 512, 0, stream>>>(
            qws, wob, (float*)d_out, bo);
    } else {
        gemm_bt<true, true, false, false><<<dim3(D_/128, M_/128, 3), 256, 0, stream>>>(
            x, Wq, Wk, Wv, qws, nullptr);

        attn_mfma<<<dim3(2 * H_ * 64 / 4), 256, 0, stream>>>(qws, kws, vws);

        gemm_bt<false, true, true, true><<<dim3(D_/128, M_/128, 1), 256, 0, stream>>>(
            qws, Wo, nullptr, nullptr, (float*)d_out, bo);
    }
}

// Round 14
// 84.617 us; speedup vs baseline: 1.1002x; 1.0144x over previous
//
#include <hip/hip_runtime.h>
#include <hip/hip_bf16.h>

// StridedAttention: y = (softmax(mask(QK^T/8)) V) Wo^T + bo, Q/K/V = x W{q,k,v}^T
// B=2 S=2048 D=1024 H=16 Dh=64 stride=64. Harness dtypes: f32 in/out.
// QKV: m201-style 256x256/BK=64 half-tile pipeline (round-13 proven).
// O-proj: 128x128/BK=64 2-phase (round-9 proven).
// Attention (NEW this round): V-block staged to LDS via gload_lds; PV B-frags from
// LDS; accO bounced through LDS; neighbor-PV + store in lane=channel layout
// (coalesced 128B V reads + 128B stores instead of per-lane scalar 2B traffic).

typedef __bf16 bf16;
typedef __attribute__((ext_vector_type(4))) __bf16 bf16x4;
typedef __attribute__((ext_vector_type(8))) __bf16 bf16x8;
typedef __attribute__((ext_vector_type(4))) float f32x4;
typedef __attribute__((ext_vector_type(4))) unsigned int u32x4;

constexpr int S_ = 2048;
constexpr int D_ = 1024;
constexpr int H_ = 16;
constexpr int DH = 64;
constexpr int M_ = 2 * S_;   // B*S = 4096 rows

__device__ __forceinline__ void gload_lds16(const bf16* g, bf16* l) {
    __builtin_amdgcn_global_load_lds(
        (const __attribute__((address_space(1))) void*)g,
        (__attribute__((address_space(3))) void*)l, 16, 0, 0);
}

#define BARRIER_FULL() do { asm volatile("" ::: "memory"); \
    __builtin_amdgcn_sched_barrier(0); \
    __builtin_amdgcn_s_barrier(); \
    __builtin_amdgcn_sched_barrier(0); \
    asm volatile("" ::: "memory"); } while (0)

#define WAIT_LGKM0() do { asm volatile("s_waitcnt lgkmcnt(0)" ::: "memory"); \
    __builtin_amdgcn_sched_barrier(0); } while (0)

#define WAIT_VM0() do { asm volatile("s_waitcnt vmcnt(0)" ::: "memory"); \
    __builtin_amdgcn_sched_barrier(0); } while (0)

#define WAIT_VM4() do { asm volatile("s_waitcnt vmcnt(4)" ::: "memory"); \
    __builtin_amdgcn_sched_barrier(0); } while (0)

// ---- half-tile stager: [128 rows][64 cols]. Pre-swizzled src slot g=(lane&7)^(lane>>3);
// LDS dest linear; reads apply slot' = sIdx ^ (row&7).
__device__ __forceinline__ void stage64(const bf16* __restrict__ G, int base_row,
                                        int kcol, bf16* lds, int wave, int lane)
{
    const int rIn = lane >> 3;                   // 0..7
    const int g   = (lane & 7) ^ rIn;            // src 16B slot
    #pragma unroll
    for (int l = 0; l < 2; ++l) {
        const int c = wave * 2 + l;              // 8-row chunk 0..15
        gload_lds16(G + (size_t)(base_row + c * 8 + rIn) * D_ + kcol + g * 8,
                    lds + c * 512);
    }
}

// ---------------- QKV: C = x @ [Wq|Wk|Wv]^T, 256x256, m201-style (r13) ----------------
__global__ __launch_bounds__(512, 1)
void gemm_qkv_8p(const bf16* __restrict__ A,    // x   [4096,1024]
                 const bf16* __restrict__ W,    // Wq|Wk|Wv [3072,1024]
                 bf16* __restrict__ C)          // 3 x [4096,1024] contiguous
{
    constexpr int BK = 64;
    constexpr int NT = D_ / BK;                    // 16 K-tiles
    constexpr int HS = 128 * BK;                   // half-tile: 16 KB
    __shared__ __align__(16) bf16 As[2][2][HS];    // 64 KB
    __shared__ __align__(16) bf16 Bs[2][2][HS];    // 64 KB

    const int tid  = threadIdx.x;
    const int wave = tid >> 6;
    const int lane = tid & 63;
    const int wm = wave >> 2;
    const int wn = wave & 3;

    const int lid = blockIdx.y * 12 + blockIdx.x;
    const int xcd = lid & 7, pos = lid >> 3;
    const int bxs = (xcd & 1) * 6 + pos % 6;
    const int bys = (xcd >> 1) * 4 + pos / 6;
    const int bm = bys * 256;
    const int bn = bxs * 256;

    const int l15 = lane & 15;
    const int hi  = lane >> 4;
    const int r7  = l15 & 7;
    const int bh  = wn >> 1;

    int aOff[2][4][2], bOff[2][2][2];
    #pragma unroll
    for (int mh = 0; mh < 2; ++mh)
        #pragma unroll
        for (int fm = 0; fm < 4; ++fm)
            #pragma unroll
            for (int kk = 0; kk < 2; ++kk)
                aOff[mh][fm][kk] = (mh * 64 + fm * 16 + l15) * 64
                                 + (((kk * 4 + hi) ^ r7) * 8);
    #pragma unroll
    for (int nh = 0; nh < 2; ++nh)
        #pragma unroll
        for (int fn = 0; fn < 2; ++fn)
            #pragma unroll
            for (int kk = 0; kk < 2; ++kk)
                bOff[nh][fn][kk] = ((wn & 1) * 64 + nh * 32 + fn * 16 + l15) * 64
                                 + (((kk * 4 + hi) ^ r7) * 8);

    f32x4 acc[8][4];
    #pragma unroll
    for (int i = 0; i < 8; ++i)
        #pragma unroll
        for (int j = 0; j < 4; ++j) acc[i][j] = f32x4{0.f, 0.f, 0.f, 0.f};

    bf16x8 aF[4][2], bF0[2][2], bF1[2][2];

#define Q16(MH, NH, BF) do { _Pragma("unroll") \
    for (int fm = 0; fm < 4; ++fm) { _Pragma("unroll") \
        for (int fn = 0; fn < 2; ++fn) { _Pragma("unroll") \
            for (int kk = 0; kk < 2; ++kk) \
                acc[(MH)*4+fm][(NH)*2+fn] = __builtin_amdgcn_mfma_f32_16x16x32_bf16( \
                    aF[fm][kk], BF[fn][kk], acc[(MH)*4+fm][(NH)*2+fn], 0, 0, 0); \
    } } } while (0)

    stage64(A, bm +   0, 0,  &As[0][0][0], wave, lane);
    stage64(A, bm + 128, 0,  &As[0][1][0], wave, lane);
    stage64(W, bn +   0, 0,  &Bs[0][0][0], wave, lane);
    stage64(W, bn + 128, 0,  &Bs[0][1][0], wave, lane);
    stage64(W, bn +   0, BK, &Bs[1][0][0], wave, lane);
    stage64(A, bm +   0, BK, &As[1][0][0], wave, lane);
    WAIT_VM4();
    BARRIER_FULL();

    for (int t = 0; t < NT; ++t) {
        const int d = t & 1;
        const bf16* aH = &As[d][wm][0];
        const bf16* bH = &Bs[d][bh][0];
        const bool pre1 = (t + 1) < NT;
        const bool pre2 = (t + 2) < NT;
        const int k1 = (t + 1) * BK, k2 = (t + 2) * BK;

        #pragma unroll
        for (int fn = 0; fn < 2; ++fn)
            #pragma unroll
            for (int kk = 0; kk < 2; ++kk)
                bF0[fn][kk] = *(const bf16x8*)(bH + bOff[0][fn][kk]);
        #pragma unroll
        for (int fm = 0; fm < 4; ++fm)
            #pragma unroll
            for (int kk = 0; kk < 2; ++kk)
                aF[fm][kk] = *(const bf16x8*)(aH + aOff[0][fm][kk]);
        if (pre1) stage64(A, bm + 128, k1, &As[d ^ 1][1][0], wave, lane);
        BARRIER_FULL(); WAIT_LGKM0();
        __builtin_amdgcn_s_setprio(1); Q16(0, 0, bF0); __builtin_amdgcn_s_setprio(0);
        BARRIER_FULL();

        #pragma unroll
        for (int fn = 0; fn < 2; ++fn)
            #pragma unroll
            for (int kk = 0; kk < 2; ++kk)
                bF1[fn][kk] = *(const bf16x8*)(bH + bOff[1][fn][kk]);
        if (pre1) stage64(W, bn + 128, k1, &Bs[d ^ 1][1][0], wave, lane);
        BARRIER_FULL(); WAIT_LGKM0();
        __builtin_amdgcn_s_setprio(1); Q16(0, 1, bF1); __builtin_amdgcn_s_setprio(0);
        BARRIER_FULL();

        #pragma unroll
        for (int fm = 0; fm < 4; ++fm)
            #pragma unroll
            for (int kk = 0; kk < 2; ++kk)
                aF[fm][kk] = *(const bf16x8*)(aH + aOff[1][fm][kk]);
        if (pre2) stage64(W, bn + 0, k2, &Bs[d][0][0], wave, lane);
        BARRIER_FULL(); WAIT_LGKM0();
        __builtin_amdgcn_s_setprio(1); Q16(1, 1, bF1); __builtin_amdgcn_s_setprio(0);
        BARRIER_FULL();

        if (pre2) stage64(A, bm + 0, k2, &As[d][0][0], wave, lane);
        __builtin_amdgcn_s_setprio(1); Q16(1, 0, bF0); __builtin_amdgcn_s_setprio(0);
        if (pre2) { WAIT_VM4(); } else { WAIT_VM0(); }
        BARRIER_FULL();
    }
#undef Q16

    #pragma unroll
    for (int i = 0; i < 8; ++i) {
        #pragma unroll
        for (int j = 0; j < 4; ++j) {
            const int n = bn + wn * 64 + j * 16 + l15;
            bf16* Cz = C + (size_t)(n >> 10) * M_ * D_;
            const int col = n & 1023;
            const int mb = bm + wm * 128 + i * 16 + hi * 4;
            #pragma unroll
            for (int r2 = 0; r2 < 4; ++r2)
                Cz[(size_t)(mb + r2) * D_ + col] = (bf16)acc[i][j][r2];
        }
    }
}

// ---------------- O-proj: Cf = AO @ Wo^T + bo, 128x128/BK=64, 8 waves (r9) ----
__global__ __launch_bounds__(512, 1)
void gemm_o_2ph(const bf16* __restrict__ A,
                const bf16* __restrict__ W,
                float* __restrict__ Cf,
                const float* __restrict__ bias)
{
    constexpr int BK = 64;
    constexpr int NT = D_ / BK;
    constexpr int TSLOT = 128 * BK;
    __shared__ __align__(16) bf16 As[3 * TSLOT];
    __shared__ __align__(16) bf16 Bs[3 * TSLOT];

    const int tid  = threadIdx.x;
    const int wave = tid >> 6;
    const int lane = tid & 63;
    const int wm = wave >> 2;
    const int wn = wave & 3;

    const int lid = blockIdx.y * 8 + blockIdx.x;
    const int xcd = lid & 7, pos = lid >> 3;
    const int bxs = (xcd & 3) * 2 + (pos & 1);
    const int bys = (xcd >> 2) * 16 + (pos >> 1);
    const int bm = bys * 128;
    const int bn = bxs * 128;

    const int l15 = lane & 15;
    const int hi  = lane >> 4;
    const int r7  = l15 & 7;

    int aOff[2][4], bOff[2][2];
    #pragma unroll
    for (int ks = 0; ks < 2; ++ks) {
        #pragma unroll
        for (int fm = 0; fm < 4; ++fm)
            aOff[ks][fm] = (wm * 64 + fm * 16 + l15) * 64 + (((ks * 4 + hi) ^ r7) * 8);
        #pragma unroll
        for (int fn = 0; fn < 2; ++fn)
            bOff[ks][fn] = (wn * 32 + fn * 16 + l15) * 64 + (((ks * 4 + hi) ^ r7) * 8);
    }

    f32x4 acc[4][2];
    #pragma unroll
    for (int i = 0; i < 4; ++i)
        #pragma unroll
        for (int j = 0; j < 2; ++j) acc[i][j] = f32x4{0.f, 0.f, 0.f, 0.f};

    bf16x8 aF0[4], aF1[4], bF[2][2];

    stage64(A, bm, 0,  As,         wave, lane);
    stage64(W, bn, 0,  Bs,         wave, lane);
    stage64(A, bm, BK, As + TSLOT, wave, lane);
    stage64(W, bn, BK, Bs + TSLOT, wave, lane);
    WAIT_VM4();
    BARRIER_FULL();

    int cur = 0;
    for (int t = 0; t < NT; ++t) {
        const int ss = (cur + 2 >= 3) ? (cur - 1) : (cur + 2);
        const bf16* aslot = As + cur * TSLOT;
        const bf16* bslot = Bs + cur * TSLOT;
        const bool pre = (t + 2) < NT;
        const int kn = (t + 2) * BK;

        #pragma unroll
        for (int ks = 0; ks < 2; ++ks)
            #pragma unroll
            for (int fn = 0; fn < 2; ++fn)
                bF[ks][fn] = *(const bf16x8*)(bslot + bOff[ks][fn]);
        #pragma unroll
        for (int fm = 0; fm < 4; ++fm)
            aF0[fm] = *(const bf16x8*)(aslot + aOff[0][fm]);
        if (pre) stage64(A, bm, kn, As + ss * TSLOT, wave, lane);
        BARRIER_FULL(); WAIT_LGKM0();
        __builtin_amdgcn_s_setprio(1);
        #pragma unroll
        for (int fm = 0; fm < 4; ++fm)
            #pragma unroll
            for (int fn = 0; fn < 2; ++fn)
                acc[fm][fn] = __builtin_amdgcn_mfma_f32_16x16x32_bf16(
                    aF0[fm], bF[0][fn], acc[fm][fn], 0, 0, 0);
        __builtin_amdgcn_s_setprio(0);
        BARRIER_FULL();

        #pragma unroll
        for (int fm = 0; fm < 4; ++fm)
            aF1[fm] = *(const bf16x8*)(aslot + aOff[1][fm]);
        if (pre) stage64(W, bn, kn, Bs + ss * TSLOT, wave, lane);
        BARRIER_FULL(); WAIT_LGKM0();
        __builtin_amdgcn_s_setprio(1);
        #pragma unroll
        for (int fm = 0; fm < 4; ++fm)
            #pragma unroll
            for (int fn = 0; fn < 2; ++fn)
                acc[fm][fn] = __builtin_amdgcn_mfma_f32_16x16x32_bf16(
                    aF1[fm], bF[1][fn], acc[fm][fn], 0, 0, 0);
        __builtin_amdgcn_s_setprio(0);
        if (pre) { WAIT_VM4(); } else { WAIT_VM0(); }
        BARRIER_FULL();
        cur = (cur + 1 >= 3) ? 0 : (cur + 1);
    }

    #pragma unroll
    for (int fm = 0; fm < 4; ++fm) {
        #pragma unroll
        for (int fn = 0; fn < 2; ++fn) {
            const int n = bn + wn * 32 + fn * 16 + l15;
            const float bv = bias[n];
            const int mb = bm + wm * 64 + fm * 16 + hi * 4;
            #pragma unroll
            for (int r2 = 0; r2 < 4; ++r2)
                Cf[(size_t)(mb + r2) * D_ + n] = acc[fm][fn][r2] + bv;
        }
    }
}

// ---------------- 128x128 2-phase GEMM (fallback path only) ----------------
template<bool AF32, bool BF32, bool CF32, bool BIAS>
__global__ __launch_bounds__(256)
void gemm_bt(const void* __restrict__ Av,
             const void* __restrict__ W0v, const void* __restrict__ W1v,
             const void* __restrict__ W2v,
             void* __restrict__ Cv, const float* __restrict__ bias)
{
    constexpr int BM = 128, BK = 64;
    constexpr int N = D_, K = D_;
    __shared__ __align__(16) bf16 As[BM * BK];
    __shared__ __align__(16) bf16 Bs[BM * BK];

    const int z = blockIdx.z;
    const void* Wv_ = (z == 0) ? W0v : (z == 1) ? W1v : W2v;

    const int tid  = threadIdx.x;
    const int wave = tid >> 6;
    const int lane = tid & 63;

    const int bm = blockIdx.y * BM;
    const int bn = blockIdx.x * BM;
    const int wr = wave >> 1;
    const int wc = wave & 1;

    f32x4 acc[4][4];
    #pragma unroll
    for (int i = 0; i < 4; ++i)
        #pragma unroll
        for (int j = 0; j < 4; ++j)
            acc[i][j] = f32x4{0.f, 0.f, 0.f, 0.f};

    const int ldRow = lane >> 3;
    const int ldCol = (lane & 7) * 8;

    for (int kt = 0; kt < K; kt += BK) {
        if (AF32) {
            const float* A = (const float*)Av;
            #pragma unroll
            for (int it = 0; it < 8; ++it) {
                const int flat = (it * 256 + tid) * 4;
                const int row = flat >> 6, col = flat & 63;
                const float4 v = *(const float4*)(A + (size_t)(bm + row) * K + kt + col);
                bf16x4 p = { (bf16)v.x, (bf16)v.y, (bf16)v.z, (bf16)v.w };
                *(bf16x4*)&As[row * BK + col] = p;
            }
        } else {
            const bf16* A = (const bf16*)Av;
            #pragma unroll
            for (int q = 0; q < 4; ++q) {
                const int c = wave * 4 + q;
                const int row = c * 8 + ldRow;
                gload_lds16(A + (size_t)(bm + row) * K + kt + ldCol, &As[c * 8 * BK]);
            }
        }
        if (BF32) {
            const float* W = (const float*)Wv_;
            #pragma unroll
            for (int it = 0; it < 8; ++it) {
                const int flat = (it * 256 + tid) * 4;
                const int row = flat >> 6, col = flat & 63;
                const float4 v = *(const float4*)(W + (size_t)(bn + row) * K + kt + col);
                bf16x4 p = { (bf16)v.x, (bf16)v.y, (bf16)v.z, (bf16)v.w };
                *(bf16x4*)&Bs[row * BK + col] = p;
            }
        } else {
            const bf16* W = (const bf16*)Wv_;
            #pragma unroll
            for (int q = 0; q < 4; ++q) {
                const int c = wave * 4 + q;
                const int row = c * 8 + ldRow;
                gload_lds16(W + (size_t)(bn + row) * K + kt + ldCol, &Bs[c * 8 * BK]);
            }
        }
        __syncthreads();
        #pragma unroll
        for (int kk = 0; kk < 2; ++kk) {
            const int k0 = kk * 32 + (lane >> 4) * 8;
            bf16x8 af[4], bfv[4];
            #pragma unroll
            for (int mi = 0; mi < 4; ++mi)
                af[mi] = *(const bf16x8*)&As[(wr * 64 + mi * 16 + (lane & 15)) * BK + k0];
            #pragma unroll
            for (int ni = 0; ni < 4; ++ni)
                bfv[ni] = *(const bf16x8*)&Bs[(wc * 64 + ni * 16 + (lane & 15)) * BK + k0];
            #pragma unroll
            for (int mi = 0; mi < 4; ++mi)
                #pragma unroll
                for (int ni = 0; ni < 4; ++ni)
                    acc[mi][ni] = __builtin_amdgcn_mfma_f32_16x16x32_bf16(
                        af[mi], bfv[ni], acc[mi][ni], 0, 0, 0);
        }
        __syncthreads();
    }

    #pragma unroll
    for (int mi = 0; mi < 4; ++mi) {
        #pragma unroll
        for (int ni = 0; ni < 4; ++ni) {
            const int n  = bn + wc * 64 + ni * 16 + (lane & 15);
            const int mb = bm + wr * 64 + mi * 16 + (lane >> 4) * 4;
            float bv = 0.f;
            if (BIAS) bv = bias[n];
            #pragma unroll
            for (int r2 = 0; r2 < 4; ++r2) {
                const int m = mb + r2;
                if (CF32) {
                    ((float*)Cv)[(size_t)m * N + n] = acc[mi][ni][r2] + bv;
                } else {
                    bf16* Cc = (bf16*)Cv + (size_t)z * M_ * D_;
                    Cc[(size_t)m * N + n] = (bf16)(acc[mi][ni][r2] + bv);
                }
            }
        }
    }
}

// ---------------- f32 -> bf16 conversion: x | Wq | Wk | Wv | Wo ----------------
__global__ __launch_bounds__(256)
void convert_to_bf16(const float* __restrict__ x,
                     const float* __restrict__ w0, const float* __restrict__ w1,
                     const float* __restrict__ w2, const float* __restrict__ w3,
                     bf16* __restrict__ out)
{
    const size_t eid = ((size_t)blockIdx.x * 256 + threadIdx.x) * 8;
    const float* src; size_t off;
    if (eid < (size_t)(1u << 22)) { src = x; off = eid; }              // x: 2^22 elems
    else {
        const size_t t = eid - (1u << 22);
        const int k = (int)(t >> 20);                                   // W: 2^20 each
        off = t & ((1u << 20) - 1);
        src = (k == 0) ? w0 : (k == 1) ? w1 : (k == 2) ? w2 : w3;
    }
    const float4 a = *(const float4*)(src + off);
    const float4 c = *(const float4*)(src + off + 4);
    bf16x8 v = { (bf16)a.x, (bf16)a.y, (bf16)a.z, (bf16)a.w,
                 (bf16)c.x, (bf16)c.y, (bf16)c.z, (bf16)c.w };
    *(bf16x8*)(out + eid) = v;
}

// ---------------- MFMA sparse attention: one wave per (b,h,r) ----------------
// NEW: V-block in LDS, accO bounced via LDS, lane=channel neighbor-PV + stores.
__device__ __forceinline__ unsigned pk2bf(float lo, float hi) {
    const unsigned a = __builtin_bit_cast(unsigned short, (bf16)lo);
    const unsigned b = __builtin_bit_cast(unsigned short, (bf16)hi);
    return a | (b << 16);
}

__global__ __launch_bounds__(256)
void attn_mfma(bf16* __restrict__ QA, const bf16* __restrict__ Kw,
               const bf16* __restrict__ Vw)
{
    // per-wave LDS: V-block 32x64 bf16 (4096 B) + bounce 32x65 f32 (8320 B)
    constexpr int WSLOT = 4096 + 8320;             // 12416 B
    __shared__ __align__(16) unsigned char smem[4 * WSLOT];

    const int lane = threadIdx.x & 63;
    const int wv   = threadIdx.x >> 6;             // wave in block 0..3
    const int wid  = blockIdx.x * 4 + wv;
    const int r = wid & 63;                        // residue class
    const int h = (wid >> 6) & (H_ - 1);
    const int b = wid >> 10;

    const int qlo = lane & 15;
    const int g   = lane >> 4;                     // quarter-wave 0..3
    const size_t rb = (size_t)b * S_;
    const int col0 = h * DH;
    const float scale = 0.125f;                    // 1/sqrt(64)

    unsigned char* ws = smem + wv * WSLOT;
    bf16*  vlds = (bf16*)ws;                       // [32][64] swizzled 16B slots
    float* bnce = (float*)(ws + 4096);             // [32][65]

    // ---- stage V residue block early (4 x gload_lds, coalesced 128B rows) ----
    {
        const int krow = lane >> 3;                // 0..7
        const int slot = lane & 7;                 // linear LDS 16B slot
        #pragma unroll
        for (int i = 0; i < 4; ++i) {
            const int k = i * 8 + krow;
            gload_lds16(Vw + (rb + (size_t)(r + 64 * k)) * D_ + col0
                           + ((slot ^ (k & 7)) * 8),
                        vlds + i * 512);
        }
    }

    // ---- S^T = K_res Q_res^T via MFMA ----
    f32x4 accS[2][2];
    #pragma unroll
    for (int a = 0; a < 2; ++a)
        #pragma unroll
        for (int c = 0; c < 2; ++c) accS[a][c] = f32x4{0.f,0.f,0.f,0.f};

    #pragma unroll
    for (int c = 0; c < 2; ++c) {                  // d-chunks of 32
        bf16x8 kf[2], qf[2];
        #pragma unroll
        for (int t = 0; t < 2; ++t) {
            const size_t row = rb + (size_t)(r + 64 * (t * 16 + qlo));
            kf[t] = *(const bf16x8*)&Kw[row * D_ + col0 + c * 32 + g * 8];
            qf[t] = *(const bf16x8*)&QA[row * D_ + col0 + c * 32 + g * 8];
        }
        #pragma unroll
        for (int kt = 0; kt < 2; ++kt)
            #pragma unroll
            for (int qt = 0; qt < 2; ++qt)
                accS[kt][qt] = __builtin_amdgcn_mfma_f32_16x16x32_bf16(
                    kf[kt], qf[qt], accS[kt][qt], 0, 0, 0);
    }

    // ---- neighbor dots (lane = (s=lane&31, side=lane>>5)) ----
    const int s_nb = lane & 31;
    const int side = lane >> 5;
    const int i_nb = r + 64 * s_nb;
    const int j_nb = side ? (i_nb + 1) : (i_nb - 1);
    const bool nbv = (unsigned)j_nb < (unsigned)S_;
    const int j_sf = nbv ? j_nb : i_nb;
    float nbd = 0.f;
    #pragma unroll
    for (int t = 0; t < 8; ++t) {
        const bf16x8 qv = *(const bf16x8*)&QA[(rb + i_nb) * D_ + col0 + t * 8];
        const bf16x8 kv = *(const bf16x8*)&Kw[(rb + j_sf) * D_ + col0 + t * 8];
        #pragma unroll
        for (int e = 0; e < 8; ++e) nbd += (float)qv[e] * (float)kv[e];
    }
    const float NEGINF = -__builtin_inff();
    float nb = nbv ? nbd * scale : NEGINF;

    // ---- softmax over 34 per query ----
    float mx[2] = { NEGINF, NEGINF };
    #pragma unroll
    for (int kt = 0; kt < 2; ++kt)
        #pragma unroll
        for (int qt = 0; qt < 2; ++qt)
            #pragma unroll
            for (int rr = 0; rr < 4; ++rr)
                mx[qt] = fmaxf(mx[qt], accS[kt][qt][rr]);
    mx[0] *= scale; mx[1] *= scale;
    mx[g & 1] = fmaxf(mx[g & 1], nb);
    #pragma unroll
    for (int x = 16; x <= 32; x <<= 1) {
        mx[0] = fmaxf(mx[0], __shfl_xor(mx[0], x));
        mx[1] = fmaxf(mx[1], __shfl_xor(mx[1], x));
    }
    float p[2][2][4];
    float sm[2] = { 0.f, 0.f };
    #pragma unroll
    for (int kt = 0; kt < 2; ++kt)
        #pragma unroll
        for (int qt = 0; qt < 2; ++qt)
            #pragma unroll
            for (int rr = 0; rr < 4; ++rr) {
                const float e = __expf(accS[kt][qt][rr] * scale - mx[qt]);
                p[kt][qt][rr] = e;
                sm[qt] += e;
            }
    float nbp = __expf(nb - mx[g & 1]);
    sm[g & 1] += nbp;
    #pragma unroll
    for (int x = 16; x <= 32; x <<= 1) {
        sm[0] += __shfl_xor(sm[0], x);
        sm[1] += __shfl_xor(sm[1], x);
    }
    const float inv[2] = { 1.f / sm[0], 1.f / sm[1] };
    #pragma unroll
    for (int kt = 0; kt < 2; ++kt)
        #pragma unroll
        for (int qt = 0; qt < 2; ++qt)
            #pragma unroll
            for (int rr = 0; rr < 4; ++rr) p[kt][qt][rr] *= inv[qt];
    nbp *= inv[g & 1];

    // ---- repack P into A-frags ----
    unsigned pk_[2][2][2];
    #pragma unroll
    for (int qt = 0; qt < 2; ++qt)
        #pragma unroll
        for (int kt = 0; kt < 2; ++kt)
            #pragma unroll
            for (int w = 0; w < 2; ++w)
                pk_[qt][kt][w] = pk2bf(p[kt][qt][2 * w], p[kt][qt][2 * w + 1]);

    const int srcA = qlo + 32 * (g & 1);
    const int srcB = srcA + 16;
    const int kts  = g >> 1;
    bf16x8 pa[2];
    #pragma unroll
    for (int qt = 0; qt < 2; ++qt) {
        u32x4 fr;
        #pragma unroll
        for (int w = 0; w < 2; ++w) {
            const unsigned a0 = (unsigned)__shfl((int)pk_[qt][0][w], srcA);
            const unsigned a1 = (unsigned)__shfl((int)pk_[qt][1][w], srcA);
            fr[w] = kts ? a1 : a0;
            const unsigned b0 = (unsigned)__shfl((int)pk_[qt][0][w], srcB);
            const unsigned b1 = (unsigned)__shfl((int)pk_[qt][1][w], srcB);
            fr[2 + w] = kts ? b1 : b0;
        }
        pa[qt] = __builtin_bit_cast(bf16x8, fr);
    }

    // ---- PV: B-frags from LDS (V-block landed; wait the gload_lds) ----
    WAIT_VM0();
    f32x4 accO[2][4];
    #pragma unroll
    for (int qt = 0; qt < 2; ++qt)
        #pragma unroll
        for (int dt = 0; dt < 4; ++dt) accO[qt][dt] = f32x4{0.f,0.f,0.f,0.f};
    #pragma unroll
    for (int dt = 0; dt < 4; ++dt) {
        bf16x8 vf;
        const int sbase = dt * 2 + (qlo >> 3);     // d>>3
        const int boff  = (qlo & 7) * 2;           // byte within 16B slot
        #pragma unroll
        for (int e = 0; e < 8; ++e) {
            const int k = g * 8 + e;
            const unsigned short u = *(const unsigned short*)
                ((const unsigned char*)vlds + k * 128 + ((sbase ^ (k & 7)) * 16) + boff);
            vf[e] = __builtin_bit_cast(bf16, u);
        }
        accO[0][dt] = __builtin_amdgcn_mfma_f32_16x16x32_bf16(pa[0], vf, accO[0][dt], 0, 0, 0);
        accO[1][dt] = __builtin_amdgcn_mfma_f32_16x16x32_bf16(pa[1], vf, accO[1][dt], 0, 0, 0);
    }

    // ---- bounce accO to LDS (MFMA layout writes) ----
    #pragma unroll
    for (int qt = 0; qt < 2; ++qt)
        #pragma unroll
        for (int rr = 0; rr < 4; ++rr) {
            const int q = qt * 16 + g * 4 + rr;
            #pragma unroll
            for (int dt = 0; dt < 4; ++dt)
                bnce[q * 65 + dt * 16 + qlo] = accO[qt][dt][rr];
        }
    WAIT_LGKM0();

    // ---- lane=channel: neighbor-PV + coalesced store (lane = d-channel) ----
    for (int q = 0; q < 32; ++q) {
        const float pm = __shfl(nbp, q);           // p(i-1), 0 if invalid
        const float pp = __shfl(nbp, q + 32);      // p(i+1), 0 if invalid
        const int iq = r + 64 * q;
        const int jm = iq > 0 ? iq - 1 : 0;
        const int jp = iq < S_ - 1 ? iq + 1 : S_ - 1;
        float o = bnce[q * 65 + lane];
        o += pm * (float)Vw[(rb + jm) * D_ + col0 + lane];
        o += pp * (float)Vw[(rb + jp) * D_ + col0 + lane];
        QA[(rb + iq) * D_ + col0 + lane] = (bf16)o;
    }
}

extern "C" void kernel_launch(void* const* d_in, const int* in_sizes, int n_in,
                              void* d_out, int out_size, void* d_ws, size_t ws_size,
                              hipStream_t stream)
{
    const float* x  = (const float*)d_in[0];
    const float* Wq = (const float*)d_in[1];
    const float* Wk = (const float*)d_in[2];
    const float* Wv = (const float*)d_in[3];
    const float* Wo = (const float*)d_in[4];
    const float* bo = (const float*)d_in[5];

    bf16* qws = (bf16*)d_ws;                        // 8 MB, becomes AO in place
    bf16* kws = qws + (size_t)M_ * D_;              // 8 MB
    bf16* vws = kws + (size_t)M_ * D_;              // 8 MB

    const bool fast = ws_size >= (size_t)40 * 1024 * 1024;

    if (fast) {
        bf16* xb  = vws + (size_t)M_ * D_;          // 8 MB
        bf16* wqb = xb + (1u << 22);                // Wq|Wk|Wv|Wo contiguous
        bf16* wob = wqb + 3 * (1u << 20);

        convert_to_bf16<<<4096, 256, 0, stream>>>(x, Wq, Wk, Wv, Wo, xb);

        gemm_qkv_8p<<<dim3(3 * D_ / 256, M_ / 256), 512, 0, stream>>>(xb, wqb, qws);

        attn_mfma<<<dim3(2 * H_ * 64 / 4), 256, 0, stream>>>(qws, kws, vws);

        gemm_o_2ph<<<dim3(D_ / 128, M_ / 128), 512, 0, stream>>>(
            qws, wob, (float*)d_out, bo);
    } else {
        gemm_bt<true, true, false, false><<<dim3(D_/128, M_/128, 3), 256, 0, stream>>>(
            x, Wq, Wk, Wv, qws, nullptr);

        attn_mfma<<<dim3(2 * H_ * 64 / 4), 256, 0, stream>>>(qws, kws, vws);

        gemm_bt<false, true, true, true><<<dim3(D_/128, M_/128, 1), 256, 0, stream>>>(
            qws, Wo, nullptr, nullptr, (float*)d_out, bo);
    }
}

// Round 15
// 83.349 us; speedup vs baseline: 1.1169x; 1.0152x over previous
//
#include <hip/hip_runtime.h>
#include <hip/hip_bf16.h>

// StridedAttention: y = (softmax(mask(QK^T/8)) V) Wo^T + bo, Q/K/V = x W{q,k,v}^T
// B=2 S=2048 D=1024 H=16 Dh=64 stride=64. Harness dtypes: f32 in/out.
// QKV (NEW): 128x128/BK=64, 8 waves, DOUBLE-buffer 64KB LDS -> 2 blocks/CU
// co-residency (TLP hides barrier/drain stalls), grid 768 = 1.5 rounds of
// 2-deep CUs. O-proj: 128x128 triple-buffer counted-vmcnt (r9 proven).
// Attention: MFMA residue block + LDS-staged V + lane=channel stores (r14).

typedef __bf16 bf16;
typedef __attribute__((ext_vector_type(4))) __bf16 bf16x4;
typedef __attribute__((ext_vector_type(8))) __bf16 bf16x8;
typedef __attribute__((ext_vector_type(4))) float f32x4;
typedef __attribute__((ext_vector_type(4))) unsigned int u32x4;

constexpr int S_ = 2048;
constexpr int D_ = 1024;
constexpr int H_ = 16;
constexpr int DH = 64;
constexpr int M_ = 2 * S_;   // B*S = 4096 rows

__device__ __forceinline__ void gload_lds16(const bf16* g, bf16* l) {
    __builtin_amdgcn_global_load_lds(
        (const __attribute__((address_space(1))) void*)g,
        (__attribute__((address_space(3))) void*)l, 16, 0, 0);
}

#define BARRIER_FULL() do { asm volatile("" ::: "memory"); \
    __builtin_amdgcn_sched_barrier(0); \
    __builtin_amdgcn_s_barrier(); \
    __builtin_amdgcn_sched_barrier(0); \
    asm volatile("" ::: "memory"); } while (0)

#define WAIT_LGKM0() do { asm volatile("s_waitcnt lgkmcnt(0)" ::: "memory"); \
    __builtin_amdgcn_sched_barrier(0); } while (0)

#define WAIT_VM0() do { asm volatile("s_waitcnt vmcnt(0)" ::: "memory"); \
    __builtin_amdgcn_sched_barrier(0); } while (0)

#define WAIT_VM4() do { asm volatile("s_waitcnt vmcnt(4)" ::: "memory"); \
    __builtin_amdgcn_sched_barrier(0); } while (0)

// ---- half-tile stager: [128 rows][64 cols]. Pre-swizzled src slot g=(lane&7)^(lane>>3);
// LDS dest linear; reads apply slot' = sIdx ^ (row&7).
__device__ __forceinline__ void stage64(const bf16* __restrict__ G, int base_row,
                                        int kcol, bf16* lds, int wave, int lane)
{
    const int rIn = lane >> 3;                   // 0..7
    const int g   = (lane & 7) ^ rIn;            // src 16B slot
    #pragma unroll
    for (int l = 0; l < 2; ++l) {
        const int c = wave * 2 + l;              // 8-row chunk 0..15
        gload_lds16(G + (size_t)(base_row + c * 8 + rIn) * D_ + kcol + g * 8,
                    lds + c * 512);
    }
}

// ---------------- QKV: C = x @ [Wq|Wk|Wv]^T, 128x128, dbuf 64KB, 2 blocks/CU ----
__global__ __launch_bounds__(512, 4)   // min 4 waves/SIMD -> VGPR<=128, 2 blk/CU
void gemm_qkv_db(const bf16* __restrict__ A,    // x   [4096,1024]
                 const bf16* __restrict__ W,    // Wq|Wk|Wv [3072,1024]
                 bf16* __restrict__ C)          // 3 x [4096,1024] contiguous
{
    constexpr int BK = 64;
    constexpr int NT = D_ / BK;                  // 16 K-tiles
    constexpr int TSLOT = 128 * BK;              // 16 KB
    __shared__ __align__(16) bf16 As[2 * TSLOT]; // 32 KB
    __shared__ __align__(16) bf16 Bs[2 * TSLOT]; // 32 KB

    const int tid  = threadIdx.x;
    const int wave = tid >> 6;                   // 0..7
    const int lane = tid & 63;
    const int wm = wave >> 2;                    // 0..1 -> 64-row half
    const int wn = wave & 3;                     // 0..3 -> 32-col quarter

    // XCD swizzle: 768 blocks, 96/XCD as 12x by 8y rect (W 3MB + A 2MB per XCD).
    const int lid = blockIdx.y * 24 + blockIdx.x;
    const int xcd = lid & 7, pos = lid >> 3;     // pos 0..95
    const int bxs = (xcd & 1) * 12 + pos % 12;
    const int bys = (xcd >> 1) * 8 + pos / 12;
    const int bm = bys * 128;
    const int bn = bxs * 128;

    const int l15 = lane & 15;
    const int hi  = lane >> 4;                   // 0..3
    const int r7  = l15 & 7;

    int aOff[2][4], bOff[2][2];
    #pragma unroll
    for (int ks = 0; ks < 2; ++ks) {
        #pragma unroll
        for (int fm = 0; fm < 4; ++fm)
            aOff[ks][fm] = (wm * 64 + fm * 16 + l15) * 64 + (((ks * 4 + hi) ^ r7) * 8);
        #pragma unroll
        for (int fn = 0; fn < 2; ++fn)
            bOff[ks][fn] = (wn * 32 + fn * 16 + l15) * 64 + (((ks * 4 + hi) ^ r7) * 8);
    }

    f32x4 acc[4][2];
    #pragma unroll
    for (int i = 0; i < 4; ++i)
        #pragma unroll
        for (int j = 0; j < 2; ++j) acc[i][j] = f32x4{0.f, 0.f, 0.f, 0.f};

    bf16x8 aF0[4], aF1[4], bF[2][2];

    // prologue: stage tile 0 only; drain; barrier
    stage64(A, bm, 0, As, wave, lane);
    stage64(W, bn, 0, Bs, wave, lane);
    WAIT_VM0();
    BARRIER_FULL();

    for (int t = 0; t < NT; ++t) {
        const int d = t & 1;
        const bf16* aslot = As + d * TSLOT;
        const bf16* bslot = Bs + d * TSLOT;
        bf16* ase = As + (d ^ 1) * TSLOT;
        bf16* bse = Bs + (d ^ 1) * TSLOT;
        const bool pre = (t + 1) < NT;
        const int kn = (t + 1) * BK;

        // ---- phase 1: read B(both ksteps) + A(ks0); stage A(t+1); 8 MFMA ----
        #pragma unroll
        for (int ks = 0; ks < 2; ++ks)
            #pragma unroll
            for (int fn = 0; fn < 2; ++fn)
                bF[ks][fn] = *(const bf16x8*)(bslot + bOff[ks][fn]);
        #pragma unroll
        for (int fm = 0; fm < 4; ++fm)
            aF0[fm] = *(const bf16x8*)(aslot + aOff[0][fm]);
        if (pre) stage64(A, bm, kn, ase, wave, lane);
        BARRIER_FULL(); WAIT_LGKM0();
        __builtin_amdgcn_s_setprio(1);
        #pragma unroll
        for (int fm = 0; fm < 4; ++fm)
            #pragma unroll
            for (int fn = 0; fn < 2; ++fn)
                acc[fm][fn] = __builtin_amdgcn_mfma_f32_16x16x32_bf16(
                    aF0[fm], bF[0][fn], acc[fm][fn], 0, 0, 0);
        __builtin_amdgcn_s_setprio(0);
        BARRIER_FULL();

        // ---- phase 2: read A(ks1); stage W(t+1); 8 MFMA; drain; barrier ----
        #pragma unroll
        for (int fm = 0; fm < 4; ++fm)
            aF1[fm] = *(const bf16x8*)(aslot + aOff[1][fm]);
        if (pre) stage64(W, bn, kn, bse, wave, lane);
        BARRIER_FULL(); WAIT_LGKM0();
        __builtin_amdgcn_s_setprio(1);
        #pragma unroll
        for (int fm = 0; fm < 4; ++fm)
            #pragma unroll
            for (int fn = 0; fn < 2; ++fn)
                acc[fm][fn] = __builtin_amdgcn_mfma_f32_16x16x32_bf16(
                    aF1[fm], bF[1][fn], acc[fm][fn], 0, 0, 0);
        __builtin_amdgcn_s_setprio(0);
        WAIT_VM0();                                // t+1 staged; TLP hides this drain
        BARRIER_FULL();
    }

    // epilogue: m = bm + wm*64 + fm*16 + hi*4 + r2 ; n = bn + wn*32 + fn*16 + l15
    #pragma unroll
    for (int fm = 0; fm < 4; ++fm) {
        #pragma unroll
        for (int fn = 0; fn < 2; ++fn) {
            const int n = bn + wn * 32 + fn * 16 + l15;
            bf16* Cz = C + (size_t)(n >> 10) * M_ * D_;
            const int col = n & 1023;
            const int mb = bm + wm * 64 + fm * 16 + hi * 4;
            #pragma unroll
            for (int r2 = 0; r2 < 4; ++r2)
                Cz[(size_t)(mb + r2) * D_ + col] = (bf16)acc[fm][fn][r2];
        }
    }
}

// ---------------- O-proj: Cf = AO @ Wo^T + bo, 128x128/BK=64, 8 waves (r9) ----
__global__ __launch_bounds__(512, 1)
void gemm_o_2ph(const bf16* __restrict__ A,
                const bf16* __restrict__ W,
                float* __restrict__ Cf,
                const float* __restrict__ bias)
{
    constexpr int BK = 64;
    constexpr int NT = D_ / BK;
    constexpr int TSLOT = 128 * BK;
    __shared__ __align__(16) bf16 As[3 * TSLOT];
    __shared__ __align__(16) bf16 Bs[3 * TSLOT];

    const int tid  = threadIdx.x;
    const int wave = tid >> 6;
    const int lane = tid & 63;
    const int wm = wave >> 2;
    const int wn = wave & 3;

    const int lid = blockIdx.y * 8 + blockIdx.x;
    const int xcd = lid & 7, pos = lid >> 3;
    const int bxs = (xcd & 3) * 2 + (pos & 1);
    const int bys = (xcd >> 2) * 16 + (pos >> 1);
    const int bm = bys * 128;
    const int bn = bxs * 128;

    const int l15 = lane & 15;
    const int hi  = lane >> 4;
    const int r7  = l15 & 7;

    int aOff[2][4], bOff[2][2];
    #pragma unroll
    for (int ks = 0; ks < 2; ++ks) {
        #pragma unroll
        for (int fm = 0; fm < 4; ++fm)
            aOff[ks][fm] = (wm * 64 + fm * 16 + l15) * 64 + (((ks * 4 + hi) ^ r7) * 8);
        #pragma unroll
        for (int fn = 0; fn < 2; ++fn)
            bOff[ks][fn] = (wn * 32 + fn * 16 + l15) * 64 + (((ks * 4 + hi) ^ r7) * 8);
    }

    f32x4 acc[4][2];
    #pragma unroll
    for (int i = 0; i < 4; ++i)
        #pragma unroll
        for (int j = 0; j < 2; ++j) acc[i][j] = f32x4{0.f, 0.f, 0.f, 0.f};

    bf16x8 aF0[4], aF1[4], bF[2][2];

    stage64(A, bm, 0,  As,         wave, lane);
    stage64(W, bn, 0,  Bs,         wave, lane);
    stage64(A, bm, BK, As + TSLOT, wave, lane);
    stage64(W, bn, BK, Bs + TSLOT, wave, lane);
    WAIT_VM4();
    BARRIER_FULL();

    int cur = 0;
    for (int t = 0; t < NT; ++t) {
        const int ss = (cur + 2 >= 3) ? (cur - 1) : (cur + 2);
        const bf16* aslot = As + cur * TSLOT;
        const bf16* bslot = Bs + cur * TSLOT;
        const bool pre = (t + 2) < NT;
        const int kn = (t + 2) * BK;

        #pragma unroll
        for (int ks = 0; ks < 2; ++ks)
            #pragma unroll
            for (int fn = 0; fn < 2; ++fn)
                bF[ks][fn] = *(const bf16x8*)(bslot + bOff[ks][fn]);
        #pragma unroll
        for (int fm = 0; fm < 4; ++fm)
            aF0[fm] = *(const bf16x8*)(aslot + aOff[0][fm]);
        if (pre) stage64(A, bm, kn, As + ss * TSLOT, wave, lane);
        BARRIER_FULL(); WAIT_LGKM0();
        __builtin_amdgcn_s_setprio(1);
        #pragma unroll
        for (int fm = 0; fm < 4; ++fm)
            #pragma unroll
            for (int fn = 0; fn < 2; ++fn)
                acc[fm][fn] = __builtin_amdgcn_mfma_f32_16x16x32_bf16(
                    aF0[fm], bF[0][fn], acc[fm][fn], 0, 0, 0);
        __builtin_amdgcn_s_setprio(0);
        BARRIER_FULL();

        #pragma unroll
        for (int fm = 0; fm < 4; ++fm)
            aF1[fm] = *(const bf16x8*)(aslot + aOff[1][fm]);
        if (pre) stage64(W, bn, kn, Bs + ss * TSLOT, wave, lane);
        BARRIER_FULL(); WAIT_LGKM0();
        __builtin_amdgcn_s_setprio(1);
        #pragma unroll
        for (int fm = 0; fm < 4; ++fm)
            #pragma unroll
            for (int fn = 0; fn < 2; ++fn)
                acc[fm][fn] = __builtin_amdgcn_mfma_f32_16x16x32_bf16(
                    aF1[fm], bF[1][fn], acc[fm][fn], 0, 0, 0);
        __builtin_amdgcn_s_setprio(0);
        if (pre) { WAIT_VM4(); } else { WAIT_VM0(); }
        BARRIER_FULL();
        cur = (cur + 1 >= 3) ? 0 : (cur + 1);
    }

    #pragma unroll
    for (int fm = 0; fm < 4; ++fm) {
        #pragma unroll
        for (int fn = 0; fn < 2; ++fn) {
            const int n = bn + wn * 32 + fn * 16 + l15;
            const float bv = bias[n];
            const int mb = bm + wm * 64 + fm * 16 + hi * 4;
            #pragma unroll
            for (int r2 = 0; r2 < 4; ++r2)
                Cf[(size_t)(mb + r2) * D_ + n] = acc[fm][fn][r2] + bv;
        }
    }
}

// ---------------- 128x128 2-phase GEMM (fallback path only) ----------------
template<bool AF32, bool BF32, bool CF32, bool BIAS>
__global__ __launch_bounds__(256)
void gemm_bt(const void* __restrict__ Av,
             const void* __restrict__ W0v, const void* __restrict__ W1v,
             const void* __restrict__ W2v,
             void* __restrict__ Cv, const float* __restrict__ bias)
{
    constexpr int BM = 128, BK = 64;
    constexpr int N = D_, K = D_;
    __shared__ __align__(16) bf16 As[BM * BK];
    __shared__ __align__(16) bf16 Bs[BM * BK];

    const int z = blockIdx.z;
    const void* Wv_ = (z == 0) ? W0v : (z == 1) ? W1v : W2v;

    const int tid  = threadIdx.x;
    const int wave = tid >> 6;
    const int lane = tid & 63;

    const int bm = blockIdx.y * BM;
    const int bn = blockIdx.x * BM;
    const int wr = wave >> 1;
    const int wc = wave & 1;

    f32x4 acc[4][4];
    #pragma unroll
    for (int i = 0; i < 4; ++i)
        #pragma unroll
        for (int j = 0; j < 4; ++j)
            acc[i][j] = f32x4{0.f, 0.f, 0.f, 0.f};

    const int ldRow = lane >> 3;
    const int ldCol = (lane & 7) * 8;

    for (int kt = 0; kt < K; kt += BK) {
        if (AF32) {
            const float* A = (const float*)Av;
            #pragma unroll
            for (int it = 0; it < 8; ++it) {
                const int flat = (it * 256 + tid) * 4;
                const int row = flat >> 6, col = flat & 63;
                const float4 v = *(const float4*)(A + (size_t)(bm + row) * K + kt + col);
                bf16x4 p = { (bf16)v.x, (bf16)v.y, (bf16)v.z, (bf16)v.w };
                *(bf16x4*)&As[row * BK + col] = p;
            }
        } else {
            const bf16* A = (const bf16*)Av;
            #pragma unroll
            for (int q = 0; q < 4; ++q) {
                const int c = wave * 4 + q;
                const int row = c * 8 + ldRow;
                gload_lds16(A + (size_t)(bm + row) * K + kt + ldCol, &As[c * 8 * BK]);
            }
        }
        if (BF32) {
            const float* W = (const float*)Wv_;
            #pragma unroll
            for (int it = 0; it < 8; ++it) {
                const int flat = (it * 256 + tid) * 4;
                const int row = flat >> 6, col = flat & 63;
                const float4 v = *(const float4*)(W + (size_t)(bn + row) * K + kt + col);
                bf16x4 p = { (bf16)v.x, (bf16)v.y, (bf16)v.z, (bf16)v.w };
                *(bf16x4*)&Bs[row * BK + col] = p;
            }
        } else {
            const bf16* W = (const bf16*)Wv_;
            #pragma unroll
            for (int q = 0; q < 4; ++q) {
                const int c = wave * 4 + q;
                const int row = c * 8 + ldRow;
                gload_lds16(W + (size_t)(bn + row) * K + kt + ldCol, &Bs[c * 8 * BK]);
            }
        }
        __syncthreads();
        #pragma unroll
        for (int kk = 0; kk < 2; ++kk) {
            const int k0 = kk * 32 + (lane >> 4) * 8;
            bf16x8 af[4], bfv[4];
            #pragma unroll
            for (int mi = 0; mi < 4; ++mi)
                af[mi] = *(const bf16x8*)&As[(wr * 64 + mi * 16 + (lane & 15)) * BK + k0];
            #pragma unroll
            for (int ni = 0; ni < 4; ++ni)
                bfv[ni] = *(const bf16x8*)&Bs[(wc * 64 + ni * 16 + (lane & 15)) * BK + k0];
            #pragma unroll
            for (int mi = 0; mi < 4; ++mi)
                #pragma unroll
                for (int ni = 0; ni < 4; ++ni)
                    acc[mi][ni] = __builtin_amdgcn_mfma_f32_16x16x32_bf16(
                        af[mi], bfv[ni], acc[mi][ni], 0, 0, 0);
        }
        __syncthreads();
    }

    #pragma unroll
    for (int mi = 0; mi < 4; ++mi) {
        #pragma unroll
        for (int ni = 0; ni < 4; ++ni) {
            const int n  = bn + wc * 64 + ni * 16 + (lane & 15);
            const int mb = bm + wr * 64 + mi * 16 + (lane >> 4) * 4;
            float bv = 0.f;
            if (BIAS) bv = bias[n];
            #pragma unroll
            for (int r2 = 0; r2 < 4; ++r2) {
                const int m = mb + r2;
                if (CF32) {
                    ((float*)Cv)[(size_t)m * N + n] = acc[mi][ni][r2] + bv;
                } else {
                    bf16* Cc = (bf16*)Cv + (size_t)z * M_ * D_;
                    Cc[(size_t)m * N + n] = (bf16)(acc[mi][ni][r2] + bv);
                }
            }
        }
    }
}

// ---------------- f32 -> bf16 conversion: x | Wq | Wk | Wv | Wo ----------------
__global__ __launch_bounds__(256)
void convert_to_bf16(const float* __restrict__ x,
                     const float* __restrict__ w0, const float* __restrict__ w1,
                     const float* __restrict__ w2, const float* __restrict__ w3,
                     bf16* __restrict__ out)
{
    const size_t eid = ((size_t)blockIdx.x * 256 + threadIdx.x) * 8;
    const float* src; size_t off;
    if (eid < (size_t)(1u << 22)) { src = x; off = eid; }              // x: 2^22 elems
    else {
        const size_t t = eid - (1u << 22);
        const int k = (int)(t >> 20);                                   // W: 2^20 each
        off = t & ((1u << 20) - 1);
        src = (k == 0) ? w0 : (k == 1) ? w1 : (k == 2) ? w2 : w3;
    }
    const float4 a = *(const float4*)(src + off);
    const float4 c = *(const float4*)(src + off + 4);
    bf16x8 v = { (bf16)a.x, (bf16)a.y, (bf16)a.z, (bf16)a.w,
                 (bf16)c.x, (bf16)c.y, (bf16)c.z, (bf16)c.w };
    *(bf16x8*)(out + eid) = v;
}

// ---------------- MFMA sparse attention: one wave per (b,h,r) (r14) ----------------
__device__ __forceinline__ unsigned pk2bf(float lo, float hi) {
    const unsigned a = __builtin_bit_cast(unsigned short, (bf16)lo);
    const unsigned b = __builtin_bit_cast(unsigned short, (bf16)hi);
    return a | (b << 16);
}

__global__ __launch_bounds__(256)
void attn_mfma(bf16* __restrict__ QA, const bf16* __restrict__ Kw,
               const bf16* __restrict__ Vw)
{
    constexpr int WSLOT = 4096 + 8320;             // V 32x64 bf16 + bounce 32x65 f32
    __shared__ __align__(16) unsigned char smem[4 * WSLOT];

    const int lane = threadIdx.x & 63;
    const int wv   = threadIdx.x >> 6;
    const int wid  = blockIdx.x * 4 + wv;
    const int r = wid & 63;
    const int h = (wid >> 6) & (H_ - 1);
    const int b = wid >> 10;

    const int qlo = lane & 15;
    const int g   = lane >> 4;
    const size_t rb = (size_t)b * S_;
    const int col0 = h * DH;
    const float scale = 0.125f;

    unsigned char* ws = smem + wv * WSLOT;
    bf16*  vlds = (bf16*)ws;
    float* bnce = (float*)(ws + 4096);

    {
        const int krow = lane >> 3;
        const int slot = lane & 7;
        #pragma unroll
        for (int i = 0; i < 4; ++i) {
            const int k = i * 8 + krow;
            gload_lds16(Vw + (rb + (size_t)(r + 64 * k)) * D_ + col0
                           + ((slot ^ (k & 7)) * 8),
                        vlds + i * 512);
        }
    }

    f32x4 accS[2][2];
    #pragma unroll
    for (int a = 0; a < 2; ++a)
        #pragma unroll
        for (int c = 0; c < 2; ++c) accS[a][c] = f32x4{0.f,0.f,0.f,0.f};

    #pragma unroll
    for (int c = 0; c < 2; ++c) {
        bf16x8 kf[2], qf[2];
        #pragma unroll
        for (int t = 0; t < 2; ++t) {
            const size_t row = rb + (size_t)(r + 64 * (t * 16 + qlo));
            kf[t] = *(const bf16x8*)&Kw[row * D_ + col0 + c * 32 + g * 8];
            qf[t] = *(const bf16x8*)&QA[row * D_ + col0 + c * 32 + g * 8];
        }
        #pragma unroll
        for (int kt = 0; kt < 2; ++kt)
            #pragma unroll
            for (int qt = 0; qt < 2; ++qt)
                accS[kt][qt] = __builtin_amdgcn_mfma_f32_16x16x32_bf16(
                    kf[kt], qf[qt], accS[kt][qt], 0, 0, 0);
    }

    const int s_nb = lane & 31;
    const int side = lane >> 5;
    const int i_nb = r + 64 * s_nb;
    const int j_nb = side ? (i_nb + 1) : (i_nb - 1);
    const bool nbv = (unsigned)j_nb < (unsigned)S_;
    const int j_sf = nbv ? j_nb : i_nb;
    float nbd = 0.f;
    #pragma unroll
    for (int t = 0; t < 8; ++t) {
        const bf16x8 qv = *(const bf16x8*)&QA[(rb + i_nb) * D_ + col0 + t * 8];
        const bf16x8 kv = *(const bf16x8*)&Kw[(rb + j_sf) * D_ + col0 + t * 8];
        #pragma unroll
        for (int e = 0; e < 8; ++e) nbd += (float)qv[e] * (float)kv[e];
    }
    const float NEGINF = -__builtin_inff();
    float nb = nbv ? nbd * scale : NEGINF;

    float mx[2] = { NEGINF, NEGINF };
    #pragma unroll
    for (int kt = 0; kt < 2; ++kt)
        #pragma unroll
        for (int qt = 0; qt < 2; ++qt)
            #pragma unroll
            for (int rr = 0; rr < 4; ++rr)
                mx[qt] = fmaxf(mx[qt], accS[kt][qt][rr]);
    mx[0] *= scale; mx[1] *= scale;
    mx[g & 1] = fmaxf(mx[g & 1], nb);
    #pragma unroll
    for (int x = 16; x <= 32; x <<= 1) {
        mx[0] = fmaxf(mx[0], __shfl_xor(mx[0], x));
        mx[1] = fmaxf(mx[1], __shfl_xor(mx[1], x));
    }
    float p[2][2][4];
    float sm[2] = { 0.f, 0.f };
    #pragma unroll
    for (int kt = 0; kt < 2; ++kt)
        #pragma unroll
        for (int qt = 0; qt < 2; ++qt)
            #pragma unroll
            for (int rr = 0; rr < 4; ++rr) {
                const float e = __expf(accS[kt][qt][rr] * scale - mx[qt]);
                p[kt][qt][rr] = e;
                sm[qt] += e;
            }
    float nbp = __expf(nb - mx[g & 1]);
    sm[g & 1] += nbp;
    #pragma unroll
    for (int x = 16; x <= 32; x <<= 1) {
        sm[0] += __shfl_xor(sm[0], x);
        sm[1] += __shfl_xor(sm[1], x);
    }
    const float inv[2] = { 1.f / sm[0], 1.f / sm[1] };
    #pragma unroll
    for (int kt = 0; kt < 2; ++kt)
        #pragma unroll
        for (int qt = 0; qt < 2; ++qt)
            #pragma unroll
            for (int rr = 0; rr < 4; ++rr) p[kt][qt][rr] *= inv[qt];
    nbp *= inv[g & 1];

    unsigned pk_[2][2][2];
    #pragma unroll
    for (int qt = 0; qt < 2; ++qt)
        #pragma unroll
        for (int kt = 0; kt < 2; ++kt)
            #pragma unroll
            for (int w = 0; w < 2; ++w)
                pk_[qt][kt][w] = pk2bf(p[kt][qt][2 * w], p[kt][qt][2 * w + 1]);

    const int srcA = qlo + 32 * (g & 1);
    const int srcB = srcA + 16;
    const int kts  = g >> 1;
    bf16x8 pa[2];
    #pragma unroll
    for (int qt = 0; qt < 2; ++qt) {
        u32x4 fr;
        #pragma unroll
        for (int w = 0; w < 2; ++w) {
            const unsigned a0 = (unsigned)__shfl((int)pk_[qt][0][w], srcA);
            const unsigned a1 = (unsigned)__shfl((int)pk_[qt][1][w], srcA);
            fr[w] = kts ? a1 : a0;
            const unsigned b0 = (unsigned)__shfl((int)pk_[qt][0][w], srcB);
            const unsigned b1 = (unsigned)__shfl((int)pk_[qt][1][w], srcB);
            fr[2 + w] = kts ? b1 : b0;
        }
        pa[qt] = __builtin_bit_cast(bf16x8, fr);
    }

    WAIT_VM0();
    f32x4 accO[2][4];
    #pragma unroll
    for (int qt = 0; qt < 2; ++qt)
        #pragma unroll
        for (int dt = 0; dt < 4; ++dt) accO[qt][dt] = f32x4{0.f,0.f,0.f,0.f};
    #pragma unroll
    for (int dt = 0; dt < 4; ++dt) {
        bf16x8 vf;
        const int sbase = dt * 2 + (qlo >> 3);
        const int boff  = (qlo & 7) * 2;
        #pragma unroll
        for (int e = 0; e < 8; ++e) {
            const int k = g * 8 + e;
            const unsigned short u = *(const unsigned short*)
                ((const unsigned char*)vlds + k * 128 + ((sbase ^ (k & 7)) * 16) + boff);
            vf[e] = __builtin_bit_cast(bf16, u);
        }
        accO[0][dt] = __builtin_amdgcn_mfma_f32_16x16x32_bf16(pa[0], vf, accO[0][dt], 0, 0, 0);
        accO[1][dt] = __builtin_amdgcn_mfma_f32_16x16x32_bf16(pa[1], vf, accO[1][dt], 0, 0, 0);
    }

    #pragma unroll
    for (int qt = 0; qt < 2; ++qt)
        #pragma unroll
        for (int rr = 0; rr < 4; ++rr) {
            const int q = qt * 16 + g * 4 + rr;
            #pragma unroll
            for (int dt = 0; dt < 4; ++dt)
                bnce[q * 65 + dt * 16 + qlo] = accO[qt][dt][rr];
        }
    WAIT_LGKM0();

    for (int q = 0; q < 32; ++q) {
        const float pm = __shfl(nbp, q);
        const float pp = __shfl(nbp, q + 32);
        const int iq = r + 64 * q;
        const int jm = iq > 0 ? iq - 1 : 0;
        const int jp = iq < S_ - 1 ? iq + 1 : S_ - 1;
        float o = bnce[q * 65 + lane];
        o += pm * (float)Vw[(rb + jm) * D_ + col0 + lane];
        o += pp * (float)Vw[(rb + jp) * D_ + col0 + lane];
        QA[(rb + iq) * D_ + col0 + lane] = (bf16)o;
    }
}

extern "C" void kernel_launch(void* const* d_in, const int* in_sizes, int n_in,
                              void* d_out, int out_size, void* d_ws, size_t ws_size,
                              hipStream_t stream)
{
    const float* x  = (const float*)d_in[0];
    const float* Wq = (const float*)d_in[1];
    const float* Wk = (const float*)d_in[2];
    const float* Wv = (const float*)d_in[3];
    const float* Wo = (const float*)d_in[4];
    const float* bo = (const float*)d_in[5];

    bf16* qws = (bf16*)d_ws;                        // 8 MB, becomes AO in place
    bf16* kws = qws + (size_t)M_ * D_;              // 8 MB
    bf16* vws = kws + (size_t)M_ * D_;              // 8 MB

    const bool fast = ws_size >= (size_t)40 * 1024 * 1024;

    if (fast) {
        bf16* xb  = vws + (size_t)M_ * D_;          // 8 MB
        bf16* wqb = xb + (1u << 22);                // Wq|Wk|Wv|Wo contiguous
        bf16* wob = wqb + 3 * (1u << 20);

        convert_to_bf16<<<4096, 256, 0, stream>>>(x, Wq, Wk, Wv, Wo, xb);

        // QKV: 768 blocks at 128x128 dbuf -> 2 blocks/CU co-resident
        gemm_qkv_db<<<dim3(3 * D_ / 128, M_ / 128), 512, 0, stream>>>(xb, wqb, qws);

        attn_mfma<<<dim3(2 * H_ * 64 / 4), 256, 0, stream>>>(qws, kws, vws);

        gemm_o_2ph<<<dim3(D_ / 128, M_ / 128), 512, 0, stream>>>(
            qws, wob, (float*)d_out, bo);
    } else {
        gemm_bt<true, true, false, false><<<dim3(D_/128, M_/128, 3), 256, 0, stream>>>(
            x, Wq, Wk, Wv, qws, nullptr);

        attn_mfma<<<dim3(2 * H_ * 64 / 4), 256, 0, stream>>>(qws, kws, vws);

        gemm_bt<false, true, true, true><<<dim3(D_/128, M_/128, 1), 256, 0, stream>>>(
            qws, Wo, nullptr, nullptr, (float*)d_out, bo);
    }
}